// Round 1
// baseline (1097.033 us; speedup 1.0000x reference)
//
#include <hip/hip_runtime.h>
#include <hip/hip_fp16.h>

// Net_83013127897371 — f32-compute implementation, f16 intermediate storage.
// Layouts: intermediates stored [b][pixel][channel] (f16) so the next kernel
// stages them into LDS with a flat coalesced float4 copy.

// ---------------- K1 / K5: 3-channel 64x64 conv3x3 + act + 2x2 maxpool ------
// block = one image, 256 threads, thread = pooled pixel (4 iterations).
template<int OC, bool LEAKY>
__global__ __launch_bounds__(256, 2)
void k_conv_in(const float* __restrict__ x, const float* __restrict__ Wg,
               const float* __restrict__ bg, const int* __restrict__ dom,
               __half* __restrict__ outp) {
  __shared__ float img[3 * 64 * 64];   // 48 KB
  __shared__ float w[OC * 27];
  __shared__ float bias[OC];
  const int bi = blockIdx.x;
  const int tid = threadIdx.x;
  int dm = 0;
  if (LEAKY) dm = dom[0];
  const float* Wsrc = Wg + dm * OC * 27;
  const float* bsrc = bg + dm * OC;
  {
    const float4* src = (const float4*)(x + (size_t)bi * 3 * 64 * 64);
    float4* dst = (float4*)img;
#pragma unroll
    for (int i = 0; i < 12; ++i) dst[tid + i * 256] = src[tid + i * 256];
    for (int i = tid; i < OC * 27; i += 256) w[i] = Wsrc[i];
    if (tid < OC) bias[tid] = bsrc[tid];
  }
  __syncthreads();
#pragma unroll 1
  for (int pp = 0; pp < 4; ++pp) {
    const int p = tid + pp * 256;          // pooled pixel 0..1023
    const int py = p >> 5, px = p & 31;
    const int r0 = 2 * py - 1, c0 = 2 * px - 1;
    float in[3][4][4];
#pragma unroll
    for (int c = 0; c < 3; ++c)
#pragma unroll
      for (int dy = 0; dy < 4; ++dy) {
        const int y = r0 + dy;
#pragma unroll
        for (int dx = 0; dx < 4; ++dx) {
          const int xx = c0 + dx;
          in[c][dy][dx] = (y >= 0 && y < 64 && xx >= 0 && xx < 64)
                              ? img[(c * 64 + y) * 64 + xx] : 0.f;
        }
      }
    __half* o = outp + ((size_t)bi * 1024 + p) * OC;
#pragma unroll 1
    for (int oc = 0; oc < OC; ++oc) {
      const float* wp = &w[oc * 27];
      float a0 = bias[oc], a1 = a0, a2 = a0, a3 = a0;
#pragma unroll
      for (int c = 0; c < 3; ++c)
#pragma unroll
        for (int ky = 0; ky < 3; ++ky)
#pragma unroll
          for (int kx = 0; kx < 3; ++kx) {
            const float wv = wp[c * 9 + ky * 3 + kx];
            a0 = fmaf(wv, in[c][ky    ][kx    ], a0);
            a1 = fmaf(wv, in[c][ky    ][kx + 1], a1);
            a2 = fmaf(wv, in[c][ky + 1][kx    ], a2);
            a3 = fmaf(wv, in[c][ky + 1][kx + 1], a3);
          }
      float m = fmaxf(fmaxf(a0, a1), fmaxf(a2, a3));
      m = LEAKY ? (m > 0.f ? m : 0.001f * m) : fmaxf(m, 0.f);
      o[oc] = __float2half(m);
    }
  }
}

// ---------------- K2 / K3: 36->36 conv3x3 + relu + 2x2 maxpool ---------------
// block = one image, thread = one pooled pixel, 4-oc accumulator blocking,
// input staged in LDS as f16 [pixel][36]; OOB -> zeroed LDS scratch row.
template<int IN_S>
__global__ __launch_bounds__((IN_S / 2) * (IN_S / 2), 2)
void k_hid(const __half* __restrict__ sin, const float* __restrict__ W,
           const float* __restrict__ bg, __half* __restrict__ sout) {
  constexpr int P = IN_S / 2;
  constexpr int NT = P * P;                 // threads per block
  constexpr int NH = IN_S * IN_S * 36;      // halves in tile
  __shared__ __half tile[NH + 64];
  const int bi = blockIdx.x;
  const int tid = threadIdx.x;
  {
    const float4* src = (const float4*)(sin + (size_t)bi * NH);
    float4* dst = (float4*)tile;
#pragma unroll
    for (int i = 0; i < NH / 8 / NT; ++i) dst[tid + i * NT] = src[tid + i * NT];
    if (tid < 32) ((__half2*)(tile + NH))[tid] = __float2half2_rn(0.f);
  }
  __syncthreads();
  const int py = tid / P, px = tid % P;
  const int r0 = 2 * py - 1, c0 = 2 * px - 1;
  const __half* ptab[4][4];
#pragma unroll
  for (int dy = 0; dy < 4; ++dy) {
    const int y = r0 + dy;
#pragma unroll
    for (int dx = 0; dx < 4; ++dx) {
      const int xx = c0 + dx;
      const bool ok = (y >= 0 && y < IN_S && xx >= 0 && xx < IN_S);
      ptab[dy][dx] = ok ? &tile[(y * IN_S + xx) * 36] : &tile[NH];
    }
  }
  __half* o = sout + ((size_t)bi * NT + tid) * 36;
#pragma unroll 1
  for (int ocg = 0; ocg < 9; ++ocg) {
    const int oc0 = ocg * 4;
    float acc[4][4];
#pragma unroll
    for (int j = 0; j < 4; ++j) {
      const float bv = bg[oc0 + j];
      acc[j][0] = bv; acc[j][1] = bv; acc[j][2] = bv; acc[j][3] = bv;
    }
#pragma unroll 1
    for (int icp = 0; icp < 18; ++icp) {    // pairs of input channels
      float2 v[4][4];
#pragma unroll
      for (int dy = 0; dy < 4; ++dy)
#pragma unroll
        for (int dx = 0; dx < 4; ++dx)
          v[dy][dx] = __half22float2(*(const __half2*)(ptab[dy][dx] + 2 * icp));
#pragma unroll
      for (int j = 0; j < 4; ++j) {
        const float* wp = W + ((size_t)(oc0 + j) * 36 + 2 * icp) * 9;
#pragma unroll
        for (int ky = 0; ky < 3; ++ky)
#pragma unroll
          for (int kx = 0; kx < 3; ++kx) {
            const float w0 = wp[ky * 3 + kx];
            const float w1 = wp[9 + ky * 3 + kx];
            acc[j][0] = fmaf(w0, v[ky    ][kx    ].x, fmaf(w1, v[ky    ][kx    ].y, acc[j][0]));
            acc[j][1] = fmaf(w0, v[ky    ][kx + 1].x, fmaf(w1, v[ky    ][kx + 1].y, acc[j][1]));
            acc[j][2] = fmaf(w0, v[ky + 1][kx    ].x, fmaf(w1, v[ky + 1][kx    ].y, acc[j][2]));
            acc[j][3] = fmaf(w0, v[ky + 1][kx + 1].x, fmaf(w1, v[ky + 1][kx + 1].y, acc[j][3]));
          }
      }
    }
#pragma unroll
    for (int j = 0; j < 4; ++j) {
      float m = fmaxf(fmaxf(acc[j][0], acc[j][1]), fmaxf(acc[j][2], acc[j][3]));
      o[oc0 + j] = __float2half(fmaxf(m, 0.f));
    }
  }
}

// ---------------- K4: shared FC [2304]->[12] + relu -------------------------
__global__ __launch_bounds__(256)
void k_fc_shared(const __half* __restrict__ s3, const float* __restrict__ W,
                 const float* __restrict__ bg, float* __restrict__ h) {
  __shared__ float xv[2304];
  const int bi = blockIdx.x;
  const int tid = threadIdx.x;
  for (int i = tid; i < 2304; i += 256) {
    const int oc = i >> 6, p = i & 63;          // reference order e = oc*64 + p
    xv[i] = __half2float(s3[((size_t)bi * 64 + p) * 36 + oc]);
  }
  __syncthreads();
  const int wv = tid >> 6, lane = tid & 63;
  for (int k = 0; k < 3; ++k) {
    const int hid = wv + 4 * k;
    float s = 0.f;
    for (int e = lane; e < 2304; e += 64)
      s = fmaf(xv[e], W[hid * 2304 + e], s);
    for (int off = 32; off > 0; off >>= 1) s += __shfl_down(s, off);
    if (lane == 0) h[bi * 12 + hid] = fmaxf(s + bg[hid], 0.f);
  }
}

// ---------------- K6: private linear [12288]->[12] --------------------------
__global__ __launch_bounds__(256)
void k_fc_priv(const __half* __restrict__ p1, const float* __restrict__ Wg,
               const float* __restrict__ bgg, const int* __restrict__ dom,
               float* __restrict__ pout) {
  __shared__ float xv[12288];   // 48 KB
  const int bi = blockIdx.x;
  const int tid = threadIdx.x;
  const int dm = dom[0];
  const float* W = Wg + (size_t)dm * 12 * 12288;
  const float* bg = bgg + dm * 12;
  for (int i = tid; i < 12288; i += 256) {
    const int oc = i >> 10, p = i & 1023;       // reference order e = oc*1024 + p
    xv[i] = __half2float(p1[((size_t)bi * 1024 + p) * 12 + oc]);
  }
  __syncthreads();
  const int wv = tid >> 6, lane = tid & 63;
  for (int k = 0; k < 3; ++k) {
    const int hid = wv + 4 * k;
    float s = 0.f;
    for (int e = lane; e < 12288; e += 64)
      s = fmaf(xv[e], W[(size_t)hid * 12288 + e], s);
    for (int off = 32; off > 0; off >>= 1) s += __shfl_down(s, off);
    if (lane == 0) pout[bi * 12 + hid] = s + bg[hid];
  }
}

// ---------------- K7: per-sample MoE heads ----------------------------------
__global__ __launch_bounds__(256)
void k_heads(const float* __restrict__ h, const float* __restrict__ p,
             const int* __restrict__ tt,
             const float* __restrict__ W1, const float* __restrict__ b1,
             const float* __restrict__ W2, const float* __restrict__ b2,
             const float* __restrict__ W3, const float* __restrict__ b3,
             float* __restrict__ out) {
  const int b = blockIdx.x * 256 + threadIdx.x;
  if (b >= 1024) return;
  const int t = tt[b];
  float xv[24];
#pragma unroll
  for (int i = 0; i < 12; ++i) xv[i] = h[b * 12 + i];
#pragma unroll
  for (int i = 0; i < 12; ++i) xv[12 + i] = p[b * 12 + i];
  float h1[28];
  const float* w1 = W1 + t * 28 * 24;
#pragma unroll 1
  for (int i = 0; i < 28; ++i) {
    float s = b1[t * 28 + i];
#pragma unroll
    for (int j = 0; j < 24; ++j) s = fmaf(w1[i * 24 + j], xv[j], s);
    h1[i] = fmaxf(s, 0.f);
  }
  float h2[14];
  const float* w2 = W2 + t * 14 * 28;
#pragma unroll 1
  for (int i = 0; i < 14; ++i) {
    float s = b2[t * 14 + i];
#pragma unroll
    for (int j = 0; j < 28; ++j) s = fmaf(w2[i * 28 + j], h1[j], s);
    h2[i] = fmaxf(s, 0.f);
  }
  const float* w3 = W3 + t * 5 * 14;
#pragma unroll
  for (int i = 0; i < 5; ++i) {
    float s = b3[t * 5 + i];
#pragma unroll
    for (int j = 0; j < 14; ++j) s = fmaf(w3[i * 14 + j], h2[j], s);
    out[b * 5 + i] = s;
  }
}

extern "C" void kernel_launch(void* const* d_in, const int* in_sizes, int n_in,
                              void* d_out, int out_size, void* d_ws, size_t ws_size,
                              hipStream_t stream) {
  const float* x_s  = (const float*)d_in[0];
  const float* x_p  = (const float*)d_in[1];
  const int*   tt   = (const int*)d_in[2];
  const int*   dom  = (const int*)d_in[3];
  const float* WinW = (const float*)d_in[4];
  const float* Winb = (const float*)d_in[5];
  const float* WhW  = (const float*)d_in[6];
  const float* Whb  = (const float*)d_in[7];
  const float* WfcW = (const float*)d_in[8];
  const float* Wfcb = (const float*)d_in[9];
  const float* PcW  = (const float*)d_in[10];
  const float* Pcb  = (const float*)d_in[11];
  const float* PlW  = (const float*)d_in[12];
  const float* Plb  = (const float*)d_in[13];
  const float* H1W  = (const float*)d_in[14];
  const float* H1b  = (const float*)d_in[15];
  const float* H2W  = (const float*)d_in[16];
  const float* H2b  = (const float*)d_in[17];
  const float* H3W  = (const float*)d_in[18];
  const float* H3b  = (const float*)d_in[19];
  float* out = (float*)d_out;

  // Workspace layout (bytes), total ~94.6 MB; p1 aliases dead s1.
  char* ws = (char*)d_ws;
  __half* s1 = (__half*)(ws + 0);           // [1024][1024][36] f16 = 75497472
  __half* s2 = (__half*)(ws + 75497472);    // [1024][256][36]  f16 = 18874368
  __half* s3 = (__half*)(ws + 94371840);    // [1024][64][36]   f16 = 4718592
  float*  hb = (float*)(ws + 99090432);     // [1024][12] f32
  float*  pb = (float*)(ws + 99139584);     // [1024][12] f32
  __half* p1 = s1;                          // reuse after k_hid<32> consumed s1

  k_conv_in<36, false><<<1024, 256, 0, stream>>>(x_s, WinW, Winb, dom, s1);
  k_hid<32><<<1024, 256, 0, stream>>>(s1, WhW, Whb, s2);
  k_hid<16><<<1024, 64, 0, stream>>>(s2, WhW, Whb, s3);
  k_fc_shared<<<1024, 256, 0, stream>>>(s3, WfcW, Wfcb, hb);
  k_conv_in<12, true><<<1024, 256, 0, stream>>>(x_p, PcW, Pcb, dom, p1);
  k_fc_priv<<<1024, 256, 0, stream>>>(p1, PlW, Plb, dom, pb);
  k_heads<<<4, 256, 0, stream>>>(hb, pb, tt, H1W, H1b, H2W, H2b, H3W, H3b, out);
}

// Round 2
// 779.572 us; speedup vs baseline: 1.4072x; 1.4072x over previous
//
#include <hip/hip_runtime.h>
#include <hip/hip_fp16.h>

typedef _Float16 half8 __attribute__((ext_vector_type(8)));
typedef float floatx4 __attribute__((ext_vector_type(4)));

// ---------------- K1 / K5: 3-channel 64x64 conv3x3 + act + 2x2 maxpool ------
template<int OC, bool LEAKY>
__global__ __launch_bounds__(256, 2)
void k_conv_in(const float* __restrict__ x, const float* __restrict__ Wg,
               const float* __restrict__ bg, const int* __restrict__ dom,
               __half* __restrict__ outp) {
  __shared__ float img[3 * 64 * 64];   // 48 KB
  __shared__ float w[OC * 27];
  __shared__ float bias[OC];
  const int bi = blockIdx.x;
  const int tid = threadIdx.x;
  int dm = 0;
  if (LEAKY) dm = dom[0];
  const float* Wsrc = Wg + dm * OC * 27;
  const float* bsrc = bg + dm * OC;
  {
    const float4* src = (const float4*)(x + (size_t)bi * 3 * 64 * 64);
    float4* dst = (float4*)img;
#pragma unroll
    for (int i = 0; i < 12; ++i) dst[tid + i * 256] = src[tid + i * 256];
    for (int i = tid; i < OC * 27; i += 256) w[i] = Wsrc[i];
    if (tid < OC) bias[tid] = bsrc[tid];
  }
  __syncthreads();
#pragma unroll 1
  for (int pp = 0; pp < 4; ++pp) {
    const int p = tid + pp * 256;
    const int py = p >> 5, px = p & 31;
    const int r0 = 2 * py - 1, c0 = 2 * px - 1;
    float in[3][4][4];
#pragma unroll
    for (int c = 0; c < 3; ++c)
#pragma unroll
      for (int dy = 0; dy < 4; ++dy) {
        const int y = r0 + dy;
#pragma unroll
        for (int dx = 0; dx < 4; ++dx) {
          const int xx = c0 + dx;
          in[c][dy][dx] = (y >= 0 && y < 64 && xx >= 0 && xx < 64)
                              ? img[(c * 64 + y) * 64 + xx] : 0.f;
        }
      }
    __half* o = outp + ((size_t)bi * 1024 + p) * OC;
#pragma unroll 1
    for (int oc = 0; oc < OC; ++oc) {
      const float* wp = &w[oc * 27];
      float a0 = bias[oc], a1 = a0, a2 = a0, a3 = a0;
#pragma unroll
      for (int c = 0; c < 3; ++c)
#pragma unroll
        for (int ky = 0; ky < 3; ++ky)
#pragma unroll
          for (int kx = 0; kx < 3; ++kx) {
            const float wv = wp[c * 9 + ky * 3 + kx];
            a0 = fmaf(wv, in[c][ky    ][kx    ], a0);
            a1 = fmaf(wv, in[c][ky    ][kx + 1], a1);
            a2 = fmaf(wv, in[c][ky + 1][kx    ], a2);
            a3 = fmaf(wv, in[c][ky + 1][kx + 1], a3);
          }
      float m = fmaxf(fmaxf(a0, a1), fmaxf(a2, a3));
      m = LEAKY ? (m > 0.f ? m : 0.001f * m) : fmaxf(m, 0.f);
      o[oc] = __float2half(m);
    }
  }
}

// ---------------- weight prepack for hid convs (run once per launch) --------
// Bpack layout: [11 slices][3 ntiles][64 lanes][8 halves]
// k-slice map: s<9: tap=s, ch=k (0..31); s==9: tap=k>>2 (0..7), ch=32+(k&3);
//              s==10: k<4 -> tap=8, ch=32+k, else 0.
__global__ void k_prepack(const float* __restrict__ W, const float* __restrict__ b,
                          __half* __restrict__ Bpack, float* __restrict__ bias48) {
  const int tid = threadIdx.x;
  for (int i = tid; i < 11 * 3 * 64 * 8; i += 256) {
    const int j = i & 7, lane = (i >> 3) & 63, nt = (i >> 9) % 3, s = i / 1536;
    const int n = lane & 15, q = lane >> 4;
    const int k = q * 8 + j;
    const int oc = nt * 16 + n;
    int tap, ch; bool valid = true;
    if (s < 9)       { tap = s;      ch = k; }
    else if (s == 9) { tap = k >> 2; ch = 32 + (k & 3); }
    else             { tap = 8;      ch = 32 + k; valid = (k < 4); }
    float v = 0.f;
    if (valid && oc < 36 && ch < 36) v = W[(oc * 36 + ch) * 9 + tap];
    Bpack[i] = __float2half(v);
  }
  if (tid < 48) bias48[tid] = (tid < 36) ? b[tid] : 0.f;
}

// ---------------- MFMA implicit-GEMM 36->36 conv3x3 + relu + 2x2 pool -------
// A-frag: A[m=lane&15][k=(lane>>4)*8+j]; C/D: col(n)=lane&15, row(m)=q*4+reg.
// LDS A record = 80 B/pixel (stride 5 x 16B chunks -> conflict-free b128 loads).
template<int IN_S>
__global__ __launch_bounds__(256, 2)
void k_hid_mfma(const __half* __restrict__ sin, const __half* __restrict__ Bpack,
                const float* __restrict__ bias48, __half* __restrict__ sout) {
  constexpr int P = IN_S / 2;
  constexpr int Wd = IN_S + 2;
  constexpr int RPW = (IN_S == 32) ? 2 : 4;   // pre-pool rows per wave
  constexpr int PRB = 4 * RPW;                // pre-pool rows per block
  constexpr int LROWS = PRB + 2;
  constexpr int HT = IN_S / 16;               // 16-px half-tiles per row
  constexpr int BPI = IN_S / PRB;             // blocks per image
  constexpr int MT = RPW * HT;                // m-tiles per wave (=4)
  constexpr int REC = 80;

  __shared__ __align__(16) char ldsA[LROWS * Wd * REC];
  __shared__ __align__(16) char ldsB[11 * 3 * 64 * 16];
  __shared__ float lbias[48];

  const int tid = threadIdx.x;
  const int b  = blockIdx.x / BPI;
  const int br = blockIdx.x % BPI;
  const int y0 = br * PRB;

  // stage B fragments + bias (L2-resident broadcast)
  {
    const uint4* src = (const uint4*)Bpack;
    uint4* dst = (uint4*)ldsB;
    for (int i = tid; i < 11 * 3 * 64; i += 256) dst[i] = src[i];
    if (tid < 48) lbias[tid] = bias48[tid];
  }
  // stage A row strip; halo cols/rows zeroed
  {
    for (int i = tid; i < LROWS * 2 * 10; i += 256) {
      const int rr = i / 20, rem = i % 20;
      const int pix = (rem >= 10) ? (Wd - 1) : 0;
      *(unsigned long long*)&ldsA[(rr * Wd + pix) * REC + (rem % 10) * 8] = 0ULL;
    }
    const char* gbase = (const char*)(sin + (size_t)b * IN_S * IN_S * 36);
#pragma unroll 1
    for (int rr = 0; rr < LROWS; ++rr) {
      const int iy = y0 - 1 + rr;
      if (iy >= 0 && iy < IN_S) {
        const char* grow = gbase + (size_t)iy * IN_S * 72;
        char* lrow = &ldsA[rr * Wd * REC + REC];   // x=0 lands at lds col 1
        for (int i = tid; i < IN_S * 9; i += 256) {
          const int pix = i / 9, p = i - pix * 9;
          *(unsigned long long*)&lrow[pix * REC + p * 8] =
              *(const unsigned long long*)&grow[i * 8];
        }
      } else {
        for (int i = tid; i < Wd * 10; i += 256)
          *(unsigned long long*)&ldsA[rr * Wd * REC + i * 8] = 0ULL;
      }
    }
  }
  __syncthreads();

  const int wave = tid >> 6, lane = tid & 63;
  const int ln = lane & 15, q = lane >> 4;

  int baseA[MT];
#pragma unroll
  for (int mt = 0; mt < MT; ++mt) {
    const int r = (IN_S == 32) ? (mt >> 1) : mt;
    const int h = (IN_S == 32) ? (mt & 1) : 0;
    const int pr = wave * RPW + r;
    const int x = h * 16 + ln;
    baseA[mt] = (pr * Wd + x) * REC + q * 16;
  }
  // remainder-slice per-lane tap offsets (b64 at ch32..35 = byte 64)
  const int tA = 2 * q, tB = 2 * q + 1;
  const int roffA = ((tA / 3) * Wd + (tA % 3)) * REC + 64;
  const int roffB = ((tB / 3) * Wd + (tB % 3)) * REC + 64;
  const int roffC = (2 * Wd + 2) * REC + 64;   // tap 8

  floatx4 acc[MT][3];
#pragma unroll
  for (int mt = 0; mt < MT; ++mt)
#pragma unroll
    for (int nt = 0; nt < 3; ++nt) acc[mt][nt] = (floatx4){0.f, 0.f, 0.f, 0.f};

  const char* lB = ldsB + lane * 16;
#pragma unroll
  for (int s = 0; s < 9; ++s) {
    const int ky = s / 3, kx = s % 3;
    const half8 B0 = *(const half8*)(lB + (s * 3 + 0) * 1024);
    const half8 B1 = *(const half8*)(lB + (s * 3 + 1) * 1024);
    const half8 B2 = *(const half8*)(lB + (s * 3 + 2) * 1024);
#pragma unroll
    for (int mt = 0; mt < MT; ++mt) {
      const half8 A = *(const half8*)(ldsA + baseA[mt] + (ky * Wd + kx) * REC);
      acc[mt][0] = __builtin_amdgcn_mfma_f32_16x16x32_f16(A, B0, acc[mt][0], 0, 0, 0);
      acc[mt][1] = __builtin_amdgcn_mfma_f32_16x16x32_f16(A, B1, acc[mt][1], 0, 0, 0);
      acc[mt][2] = __builtin_amdgcn_mfma_f32_16x16x32_f16(A, B2, acc[mt][2], 0, 0, 0);
    }
  }
#pragma unroll
  for (int s = 9; s <= 10; ++s) {
    const half8 B0 = *(const half8*)(lB + (s * 3 + 0) * 1024);
    const half8 B1 = *(const half8*)(lB + (s * 3 + 1) * 1024);
    const half8 B2 = *(const half8*)(lB + (s * 3 + 2) * 1024);
    const int oA = (s == 9) ? roffA : roffC;
    const int oB = (s == 9) ? roffB : roffC;
#pragma unroll
    for (int mt = 0; mt < MT; ++mt) {
      union { half8 h; uint2 u[2]; } au;
      au.u[0] = *(const uint2*)(ldsA + baseA[mt] + oA);
      au.u[1] = *(const uint2*)(ldsA + baseA[mt] + oB);
      acc[mt][0] = __builtin_amdgcn_mfma_f32_16x16x32_f16(au.h, B0, acc[mt][0], 0, 0, 0);
      acc[mt][1] = __builtin_amdgcn_mfma_f32_16x16x32_f16(au.h, B1, acc[mt][1], 0, 0, 0);
      acc[mt][2] = __builtin_amdgcn_mfma_f32_16x16x32_f16(au.h, B2, acc[mt][2], 0, 0, 0);
    }
  }

  // epilogue: bias + relu + in-lane 2x2 pool + store ([b][pixel][36] f16)
  float bv[3];
#pragma unroll
  for (int nt = 0; nt < 3; ++nt) bv[nt] = lbias[nt * 16 + ln];
  __half* outb = sout + (size_t)b * P * P * 36;
#pragma unroll
  for (int pp = 0; pp < RPW / 2; ++pp) {
    const int py = (y0 + wave * RPW) / 2 + pp;
#pragma unroll
    for (int h = 0; h < HT; ++h) {
      const int mtA = (IN_S == 32) ? ((2 * pp) * 2 + h) : (2 * pp);
      const int mtB = (IN_S == 32) ? ((2 * pp + 1) * 2 + h) : (2 * pp + 1);
#pragma unroll
      for (int nt = 0; nt < 3; ++nt) {
        const int oc = nt * 16 + ln;
        if (oc < 36) {
          const floatx4 cA = acc[mtA][nt], cB = acc[mtB][nt];
          const float v0 = fmaxf(fmaxf(fmaxf(cA.x, cA.y), fmaxf(cB.x, cB.y)) + bv[nt], 0.f);
          const float v1 = fmaxf(fmaxf(fmaxf(cA.z, cA.w), fmaxf(cB.z, cB.w)) + bv[nt], 0.f);
          const int px = h * 8 + q * 2;
          outb[(py * P + px) * 36 + oc]     = __float2half(v0);
          outb[(py * P + px + 1) * 36 + oc] = __float2half(v1);
        }
      }
    }
  }
}

// ---------------- K4: shared FC [2304]->[12] + relu -------------------------
__global__ __launch_bounds__(256)
void k_fc_shared(const __half* __restrict__ s3, const float* __restrict__ W,
                 const float* __restrict__ bg, float* __restrict__ h) {
  __shared__ float xv[2304];
  const int bi = blockIdx.x;
  const int tid = threadIdx.x;
  for (int i = tid; i < 2304; i += 256) {
    const int oc = i >> 6, p = i & 63;
    xv[i] = __half2float(s3[((size_t)bi * 64 + p) * 36 + oc]);
  }
  __syncthreads();
  const int wv = tid >> 6, lane = tid & 63;
  for (int k = 0; k < 3; ++k) {
    const int hid = wv + 4 * k;
    float s = 0.f;
    for (int e = lane; e < 2304; e += 64)
      s = fmaf(xv[e], W[hid * 2304 + e], s);
    for (int off = 32; off > 0; off >>= 1) s += __shfl_down(s, off);
    if (lane == 0) h[bi * 12 + hid] = fmaxf(s + bg[hid], 0.f);
  }
}

// ---------------- K6: private linear [12288]->[12] --------------------------
__global__ __launch_bounds__(256)
void k_fc_priv(const __half* __restrict__ p1, const float* __restrict__ Wg,
               const float* __restrict__ bgg, const int* __restrict__ dom,
               float* __restrict__ pout) {
  __shared__ float xv[12288];
  const int bi = blockIdx.x;
  const int tid = threadIdx.x;
  const int dm = dom[0];
  const float* W = Wg + (size_t)dm * 12 * 12288;
  const float* bg = bgg + dm * 12;
  for (int i = tid; i < 12288; i += 256) {
    const int oc = i >> 10, p = i & 1023;
    xv[i] = __half2float(p1[((size_t)bi * 1024 + p) * 12 + oc]);
  }
  __syncthreads();
  const int wv = tid >> 6, lane = tid & 63;
  for (int k = 0; k < 3; ++k) {
    const int hid = wv + 4 * k;
    float s = 0.f;
    for (int e = lane; e < 12288; e += 64)
      s = fmaf(xv[e], W[(size_t)hid * 12288 + e], s);
    for (int off = 32; off > 0; off >>= 1) s += __shfl_down(s, off);
    if (lane == 0) pout[bi * 12 + hid] = s + bg[hid];
  }
}

// ---------------- K7: per-sample MoE heads ----------------------------------
__global__ __launch_bounds__(256)
void k_heads(const float* __restrict__ h, const float* __restrict__ p,
             const int* __restrict__ tt,
             const float* __restrict__ W1, const float* __restrict__ b1,
             const float* __restrict__ W2, const float* __restrict__ b2,
             const float* __restrict__ W3, const float* __restrict__ b3,
             float* __restrict__ out) {
  const int b = blockIdx.x * 256 + threadIdx.x;
  if (b >= 1024) return;
  const int t = tt[b];
  float xv[24];
#pragma unroll
  for (int i = 0; i < 12; ++i) xv[i] = h[b * 12 + i];
#pragma unroll
  for (int i = 0; i < 12; ++i) xv[12 + i] = p[b * 12 + i];
  float h1[28];
  const float* w1 = W1 + t * 28 * 24;
#pragma unroll 1
  for (int i = 0; i < 28; ++i) {
    float s = b1[t * 28 + i];
#pragma unroll
    for (int j = 0; j < 24; ++j) s = fmaf(w1[i * 24 + j], xv[j], s);
    h1[i] = fmaxf(s, 0.f);
  }
  float h2[14];
  const float* w2 = W2 + t * 14 * 28;
#pragma unroll 1
  for (int i = 0; i < 14; ++i) {
    float s = b2[t * 14 + i];
#pragma unroll
    for (int j = 0; j < 28; ++j) s = fmaf(w2[i * 28 + j], h1[j], s);
    h2[i] = fmaxf(s, 0.f);
  }
  const float* w3 = W3 + t * 5 * 14;
#pragma unroll
  for (int i = 0; i < 5; ++i) {
    float s = b3[t * 5 + i];
#pragma unroll
    for (int j = 0; j < 14; ++j) s = fmaf(w3[i * 14 + j], h2[j], s);
    out[b * 5 + i] = s;
  }
}

extern "C" void kernel_launch(void* const* d_in, const int* in_sizes, int n_in,
                              void* d_out, int out_size, void* d_ws, size_t ws_size,
                              hipStream_t stream) {
  const float* x_s  = (const float*)d_in[0];
  const float* x_p  = (const float*)d_in[1];
  const int*   tt   = (const int*)d_in[2];
  const int*   dom  = (const int*)d_in[3];
  const float* WinW = (const float*)d_in[4];
  const float* Winb = (const float*)d_in[5];
  const float* WhW  = (const float*)d_in[6];
  const float* Whb  = (const float*)d_in[7];
  const float* WfcW = (const float*)d_in[8];
  const float* Wfcb = (const float*)d_in[9];
  const float* PcW  = (const float*)d_in[10];
  const float* Pcb  = (const float*)d_in[11];
  const float* PlW  = (const float*)d_in[12];
  const float* Plb  = (const float*)d_in[13];
  const float* H1W  = (const float*)d_in[14];
  const float* H1b  = (const float*)d_in[15];
  const float* H2W  = (const float*)d_in[16];
  const float* H2b  = (const float*)d_in[17];
  const float* H3W  = (const float*)d_in[18];
  const float* H3b  = (const float*)d_in[19];
  float* out = (float*)d_out;

  char* ws = (char*)d_ws;
  __half* s1 = (__half*)(ws + 0);           // [1024][1024][36] f16
  __half* s2 = (__half*)(ws + 75497472);    // [1024][256][36]  f16
  __half* s3 = (__half*)(ws + 94371840);    // [1024][64][36]   f16
  float*  hb = (float*)(ws + 99090432);     // [1024][12] f32
  float*  pb = (float*)(ws + 99139584);     // [1024][12] f32
  __half* Bp = (__half*)(ws + 99188736);    // [11][3][64][8] f16 = 33792 B
  float*  b48 = (float*)(ws + 99222528);    // [48] f32
  __half* p1 = s1;                          // reuse after k_hid_mfma<32> consumed s1

  k_prepack<<<1, 256, 0, stream>>>(WhW, Whb, Bp, b48);
  k_conv_in<36, false><<<1024, 256, 0, stream>>>(x_s, WinW, Winb, dom, s1);
  k_hid_mfma<32><<<4096, 256, 0, stream>>>(s1, Bp, b48, s2);
  k_hid_mfma<16><<<1024, 256, 0, stream>>>(s2, Bp, b48, s3);
  k_fc_shared<<<1024, 256, 0, stream>>>(s3, WfcW, Wfcb, hb);
  k_conv_in<12, true><<<1024, 256, 0, stream>>>(x_p, PcW, Pcb, dom, p1);
  k_fc_priv<<<1024, 256, 0, stream>>>(p1, PlW, Plb, dom, pb);
  k_heads<<<4, 256, 0, stream>>>(hb, pb, tt, H1W, H1b, H2W, H2b, H3W, H3b, out);
}

// Round 3
// 548.646 us; speedup vs baseline: 1.9995x; 1.4209x over previous
//
#include <hip/hip_runtime.h>
#include <hip/hip_fp16.h>

typedef _Float16 half8 __attribute__((ext_vector_type(8)));
typedef float floatx4 __attribute__((ext_vector_type(4)));

// ---------------- K1 / K5: 3-channel 64x64 conv3x3 + act + 2x2 maxpool ------
// Padded LDS image (halo zeroed, +4 left pad for aligned float4 staging),
// weights read via wave-uniform global indices (scalar loads).
template<int OC, bool LEAKY>
__global__ __launch_bounds__(256, 2)
void k_conv_in(const float* __restrict__ xin, const float* __restrict__ Wg,
               const float* __restrict__ bg, const int* __restrict__ dom,
               __half* __restrict__ outp) {
  __shared__ float img[3 * 66 * 72];   // 57024 B
  const int bi = blockIdx.x, tid = threadIdx.x;
  int dm = 0;
  if (LEAKY) dm = dom[0];
  const float* Wsrc = Wg + dm * OC * 27;
  const float* bsrc = bg + dm * OC;
  // zero halo: rows y=0,65 (all x), cols x=3,68 (y=1..64)
  for (int i = tid; i < 816; i += 256) {
    const int c = i / 272, r = i % 272;
    int y, xx;
    if (r < 144) { y = (r < 72) ? 0 : 65; xx = r % 72; }
    else { const int rr = r - 144; xx = (rr < 64) ? 3 : 68; y = 1 + (rr & 63); }
    img[(c * 66 + y) * 72 + xx] = 0.f;
  }
  {
    const float4* src = (const float4*)(xin + (size_t)bi * 12288);
    for (int i = tid; i < 3072; i += 256) {
      const int c = i >> 10, rem = i & 1023, y = rem >> 4, xq = rem & 15;
      *(float4*)&img[(c * 66 + y + 1) * 72 + 4 + xq * 4] = src[i];
    }
  }
  __syncthreads();
#pragma unroll 1
  for (int pp = 0; pp < 4; ++pp) {
    const int p = tid + pp * 256;
    const int py = p >> 5, px = p & 31;
    float in[3][4][4];
#pragma unroll
    for (int c = 0; c < 3; ++c)
#pragma unroll
      for (int dy = 0; dy < 4; ++dy)
#pragma unroll
        for (int dx = 0; dx < 4; ++dx)
          in[c][dy][dx] = img[(c * 66 + 2 * py + dy) * 72 + 2 * px + 3 + dx];
    __half* o = outp + ((size_t)bi * 1024 + p) * OC;
#pragma unroll 1
    for (int oc0 = 0; oc0 < OC; oc0 += 2) {
      float a[2][4];
#pragma unroll
      for (int j = 0; j < 2; ++j) {
        const float bv = bsrc[oc0 + j];
        a[j][0] = bv; a[j][1] = bv; a[j][2] = bv; a[j][3] = bv;
      }
#pragma unroll
      for (int c = 0; c < 3; ++c)
#pragma unroll
        for (int ky = 0; ky < 3; ++ky)
#pragma unroll
          for (int kx = 0; kx < 3; ++kx) {
#pragma unroll
            for (int j = 0; j < 2; ++j) {
              const float wv = Wsrc[(oc0 + j) * 27 + c * 9 + ky * 3 + kx];
              a[j][0] = fmaf(wv, in[c][ky    ][kx    ], a[j][0]);
              a[j][1] = fmaf(wv, in[c][ky    ][kx + 1], a[j][1]);
              a[j][2] = fmaf(wv, in[c][ky + 1][kx    ], a[j][2]);
              a[j][3] = fmaf(wv, in[c][ky + 1][kx + 1], a[j][3]);
            }
          }
      __half2 st;
#pragma unroll
      for (int j = 0; j < 2; ++j) {
        float m = fmaxf(fmaxf(a[j][0], a[j][1]), fmaxf(a[j][2], a[j][3]));
        m = LEAKY ? (m > 0.f ? m : 0.001f * m) : fmaxf(m, 0.f);
        ((__half*)&st)[j] = __float2half(m);
      }
      *(__half2*)(o + oc0) = st;
    }
  }
}

// ---------------- weight prepack for hid convs ------------------------------
// Bpack layout: [11 slices][3 ntiles][64 lanes][8 halves]
__global__ void k_prepack(const float* __restrict__ W, const float* __restrict__ b,
                          __half* __restrict__ Bpack, float* __restrict__ bias48) {
  const int tid = threadIdx.x;
  for (int i = tid; i < 11 * 3 * 64 * 8; i += 256) {
    const int j = i & 7, lane = (i >> 3) & 63, nt = (i >> 9) % 3, s = i / 1536;
    const int n = lane & 15, q = lane >> 4;
    const int k = q * 8 + j;
    const int oc = nt * 16 + n;
    int tap, ch; bool valid = true;
    if (s < 9)       { tap = s;      ch = k; }
    else if (s == 9) { tap = k >> 2; ch = 32 + (k & 3); }
    else             { tap = 8;      ch = 32 + k; valid = (k < 4); }
    float v = 0.f;
    if (valid && oc < 36 && ch < 36) v = W[(oc * 36 + ch) * 9 + tap];
    Bpack[i] = __float2half(v);
  }
  if (tid < 48) bias48[tid] = (tid < 36) ? b[tid] : 0.f;
}

// ---------------- FC weight prepack (fragment order, domain-selected) -------
// Bpriv: [384][64][8] from Pl_W[dm], storage k = pix*12+oc, ref e = oc*1024+pix
// Bsh:   [72][64][8]  from Ws_fc_W,  storage k = pix*36+oc, ref e = oc*64+pix
__global__ void k_prepack_fc(const float* __restrict__ PlW, const float* __restrict__ Plb,
                             const int* __restrict__ dom,
                             const float* __restrict__ WfcW, const float* __restrict__ Wfcb,
                             __half* __restrict__ Bpriv, __half* __restrict__ Bsh,
                             float* __restrict__ bpriv, float* __restrict__ bsh) {
  const int dm = dom[0];
  const int gid = blockIdx.x * 256 + threadIdx.x;
  const int stride = gridDim.x * 256;
  for (int i = gid; i < 384 * 512; i += stride) {
    const int j = i & 7, lane = (i >> 3) & 63, s = i >> 9;
    const int n = lane & 15, q = lane >> 4;
    const int k = s * 32 + q * 8 + j;
    const int pix = k / 12, oc = k - pix * 12;
    float v = 0.f;
    if (n < 12) v = PlW[((size_t)dm * 12 + n) * 12288 + oc * 1024 + pix];
    Bpriv[i] = __float2half(v);
  }
  for (int i = gid; i < 72 * 512; i += stride) {
    const int j = i & 7, lane = (i >> 3) & 63, s = i >> 9;
    const int n = lane & 15, q = lane >> 4;
    const int k = s * 32 + q * 8 + j;
    const int pix = k / 36, oc = k - pix * 36;
    float v = 0.f;
    if (n < 12) v = WfcW[n * 2304 + oc * 64 + pix];
    Bsh[i] = __float2half(v);
  }
  if (gid < 12) { bpriv[gid] = Plb[dm * 12 + gid]; bsh[gid] = Wfcb[gid]; }
}

// ---------------- MFMA FC: one wave = one 16-row m-tile, K-split ------------
// A frag: A[m=lane&15][k=(lane>>4)*8+j] direct from global (rows contiguous).
// D: row(m)=q*4+reg, col(n)=lane&15.
template<int SL>
__global__ __launch_bounds__(64)
void k_fc_mfma(const __half* __restrict__ A, const __half* __restrict__ Bf,
               float* __restrict__ part, int Khalves) {
  const int ks = blockIdx.x, mt = blockIdx.y;
  const int lane = threadIdx.x, ln = lane & 15, q = lane >> 4;
  const __half* arow = A + (size_t)(mt * 16 + ln) * Khalves + ks * SL * 32 + q * 8;
  const __half* bptr = Bf + ((size_t)ks * SL * 64 + lane) * 8;
  floatx4 acc = {0.f, 0.f, 0.f, 0.f};
#pragma unroll
  for (int s = 0; s < SL; ++s) {
    const half8 a = *(const half8*)(arow + s * 32);
    const half8 b = *(const half8*)(bptr + s * 512);
    acc = __builtin_amdgcn_mfma_f32_16x16x32_f16(a, b, acc, 0, 0, 0);
  }
  float* pr = part + ((size_t)ks * 1024 + mt * 16) * 16 + ln;
#pragma unroll
  for (int r = 0; r < 4; ++r) pr[(q * 4 + r) * 16] = acc[r];
}

template<int KS, bool RELU>
__global__ __launch_bounds__(256)
void k_fc_reduce(const float* __restrict__ part, const float* __restrict__ bias,
                 float* __restrict__ outv) {
  const int i = blockIdx.x * 256 + threadIdx.x;
  if (i >= 1024 * 12) return;
  const int b = i / 12, hid = i - b * 12;
  float s = bias[hid];
#pragma unroll
  for (int k = 0; k < KS; ++k) s += part[((size_t)k * 1024 + b) * 16 + hid];
  outv[i] = RELU ? fmaxf(s, 0.f) : s;
}

// ---------------- MFMA implicit-GEMM 36->36 conv3x3 + relu + 2x2 pool -------
template<int IN_S>
__global__ __launch_bounds__(256, 2)
void k_hid_mfma(const __half* __restrict__ sin, const __half* __restrict__ Bpack,
                const float* __restrict__ bias48, __half* __restrict__ sout) {
  constexpr int P = IN_S / 2;
  constexpr int Wd = IN_S + 2;
  constexpr int RPW = (IN_S == 32) ? 2 : 4;
  constexpr int PRB = 4 * RPW;
  constexpr int LROWS = PRB + 2;
  constexpr int HT = IN_S / 16;
  constexpr int BPI = IN_S / PRB;
  constexpr int MT = RPW * HT;
  constexpr int REC = 80;

  __shared__ __align__(16) char ldsA[LROWS * Wd * REC];
  __shared__ __align__(16) char ldsB[11 * 3 * 64 * 16];
  __shared__ float lbias[48];

  const int tid = threadIdx.x;
  const int b  = blockIdx.x / BPI;
  const int br = blockIdx.x % BPI;
  const int y0 = br * PRB;

  {
    const uint4* src = (const uint4*)Bpack;
    uint4* dst = (uint4*)ldsB;
    for (int i = tid; i < 11 * 3 * 64; i += 256) dst[i] = src[i];
    if (tid < 48) lbias[tid] = bias48[tid];
  }
  {
    for (int i = tid; i < LROWS * 2 * 10; i += 256) {
      const int rr = i / 20, rem = i % 20;
      const int pix = (rem >= 10) ? (Wd - 1) : 0;
      *(unsigned long long*)&ldsA[(rr * Wd + pix) * REC + (rem % 10) * 8] = 0ULL;
    }
    const char* gbase = (const char*)(sin + (size_t)b * IN_S * IN_S * 36);
#pragma unroll 1
    for (int rr = 0; rr < LROWS; ++rr) {
      const int iy = y0 - 1 + rr;
      if (iy >= 0 && iy < IN_S) {
        const char* grow = gbase + (size_t)iy * IN_S * 72;
        char* lrow = &ldsA[rr * Wd * REC + REC];
        for (int i = tid; i < IN_S * 9; i += 256) {
          const int pix = i / 9, p = i - pix * 9;
          *(unsigned long long*)&lrow[pix * REC + p * 8] =
              *(const unsigned long long*)&grow[i * 8];
        }
      } else {
        for (int i = tid; i < Wd * 10; i += 256)
          *(unsigned long long*)&ldsA[rr * Wd * REC + i * 8] = 0ULL;
      }
    }
  }
  __syncthreads();

  const int wave = tid >> 6, lane = tid & 63;
  const int ln = lane & 15, q = lane >> 4;

  int baseA[MT];
#pragma unroll
  for (int mt = 0; mt < MT; ++mt) {
    const int r = (IN_S == 32) ? (mt >> 1) : mt;
    const int h = (IN_S == 32) ? (mt & 1) : 0;
    const int pr = wave * RPW + r;
    const int x = h * 16 + ln;
    baseA[mt] = (pr * Wd + x) * REC + q * 16;
  }
  const int tA = 2 * q, tB = 2 * q + 1;
  const int roffA = ((tA / 3) * Wd + (tA % 3)) * REC + 64;
  const int roffB = ((tB / 3) * Wd + (tB % 3)) * REC + 64;
  const int roffC = (2 * Wd + 2) * REC + 64;

  floatx4 acc[MT][3];
#pragma unroll
  for (int mt = 0; mt < MT; ++mt)
#pragma unroll
    for (int nt = 0; nt < 3; ++nt) acc[mt][nt] = (floatx4){0.f, 0.f, 0.f, 0.f};

  const char* lB = ldsB + lane * 16;
#pragma unroll
  for (int s = 0; s < 9; ++s) {
    const int ky = s / 3, kx = s % 3;
    const half8 B0 = *(const half8*)(lB + (s * 3 + 0) * 1024);
    const half8 B1 = *(const half8*)(lB + (s * 3 + 1) * 1024);
    const half8 B2 = *(const half8*)(lB + (s * 3 + 2) * 1024);
#pragma unroll
    for (int mt = 0; mt < MT; ++mt) {
      const half8 A = *(const half8*)(ldsA + baseA[mt] + (ky * Wd + kx) * REC);
      acc[mt][0] = __builtin_amdgcn_mfma_f32_16x16x32_f16(A, B0, acc[mt][0], 0, 0, 0);
      acc[mt][1] = __builtin_amdgcn_mfma_f32_16x16x32_f16(A, B1, acc[mt][1], 0, 0, 0);
      acc[mt][2] = __builtin_amdgcn_mfma_f32_16x16x32_f16(A, B2, acc[mt][2], 0, 0, 0);
    }
  }
#pragma unroll
  for (int s = 9; s <= 10; ++s) {
    const half8 B0 = *(const half8*)(lB + (s * 3 + 0) * 1024);
    const half8 B1 = *(const half8*)(lB + (s * 3 + 1) * 1024);
    const half8 B2 = *(const half8*)(lB + (s * 3 + 2) * 1024);
    const int oA = (s == 9) ? roffA : roffC;
    const int oB = (s == 9) ? roffB : roffC;
#pragma unroll
    for (int mt = 0; mt < MT; ++mt) {
      union { half8 h; uint2 u[2]; } au;
      au.u[0] = *(const uint2*)(ldsA + baseA[mt] + oA);
      au.u[1] = *(const uint2*)(ldsA + baseA[mt] + oB);
      acc[mt][0] = __builtin_amdgcn_mfma_f32_16x16x32_f16(au.h, B0, acc[mt][0], 0, 0, 0);
      acc[mt][1] = __builtin_amdgcn_mfma_f32_16x16x32_f16(au.h, B1, acc[mt][1], 0, 0, 0);
      acc[mt][2] = __builtin_amdgcn_mfma_f32_16x16x32_f16(au.h, B2, acc[mt][2], 0, 0, 0);
    }
  }

  float bv[3];
#pragma unroll
  for (int nt = 0; nt < 3; ++nt) bv[nt] = lbias[nt * 16 + ln];
  __half* outb = sout + (size_t)b * P * P * 36;
#pragma unroll
  for (int pp = 0; pp < RPW / 2; ++pp) {
    const int py = (y0 + wave * RPW) / 2 + pp;
#pragma unroll
    for (int h = 0; h < HT; ++h) {
      const int mtA = (IN_S == 32) ? ((2 * pp) * 2 + h) : (2 * pp);
      const int mtB = (IN_S == 32) ? ((2 * pp + 1) * 2 + h) : (2 * pp + 1);
#pragma unroll
      for (int nt = 0; nt < 3; ++nt) {
        const int oc = nt * 16 + ln;
        if (oc < 36) {
          const floatx4 cA = acc[mtA][nt], cB = acc[mtB][nt];
          const float v0 = fmaxf(fmaxf(fmaxf(cA.x, cA.y), fmaxf(cB.x, cB.y)) + bv[nt], 0.f);
          const float v1 = fmaxf(fmaxf(fmaxf(cA.z, cA.w), fmaxf(cB.z, cB.w)) + bv[nt], 0.f);
          const int px = h * 8 + q * 2;
          outb[(py * P + px) * 36 + oc]     = __float2half(v0);
          outb[(py * P + px + 1) * 36 + oc] = __float2half(v1);
        }
      }
    }
  }
}

// ---------------- K7: per-sample MoE heads ----------------------------------
__global__ __launch_bounds__(256)
void k_heads(const float* __restrict__ h, const float* __restrict__ p,
             const int* __restrict__ tt,
             const float* __restrict__ W1, const float* __restrict__ b1,
             const float* __restrict__ W2, const float* __restrict__ b2,
             const float* __restrict__ W3, const float* __restrict__ b3,
             float* __restrict__ out) {
  const int b = blockIdx.x * 256 + threadIdx.x;
  if (b >= 1024) return;
  const int t = tt[b];
  float xv[24];
#pragma unroll
  for (int i = 0; i < 12; ++i) xv[i] = h[b * 12 + i];
#pragma unroll
  for (int i = 0; i < 12; ++i) xv[12 + i] = p[b * 12 + i];
  float h1[28];
  const float* w1 = W1 + t * 28 * 24;
#pragma unroll 1
  for (int i = 0; i < 28; ++i) {
    float s = b1[t * 28 + i];
#pragma unroll
    for (int j = 0; j < 24; ++j) s = fmaf(w1[i * 24 + j], xv[j], s);
    h1[i] = fmaxf(s, 0.f);
  }
  float h2[14];
  const float* w2 = W2 + t * 14 * 28;
#pragma unroll 1
  for (int i = 0; i < 14; ++i) {
    float s = b2[t * 14 + i];
#pragma unroll
    for (int j = 0; j < 28; ++j) s = fmaf(w2[i * 28 + j], h1[j], s);
    h2[i] = fmaxf(s, 0.f);
  }
  const float* w3 = W3 + t * 5 * 14;
#pragma unroll
  for (int i = 0; i < 5; ++i) {
    float s = b3[t * 5 + i];
#pragma unroll
    for (int j = 0; j < 14; ++j) s = fmaf(w3[i * 14 + j], h2[j], s);
    out[b * 5 + i] = s;
  }
}

extern "C" void kernel_launch(void* const* d_in, const int* in_sizes, int n_in,
                              void* d_out, int out_size, void* d_ws, size_t ws_size,
                              hipStream_t stream) {
  const float* x_s  = (const float*)d_in[0];
  const float* x_p  = (const float*)d_in[1];
  const int*   tt   = (const int*)d_in[2];
  const int*   dom  = (const int*)d_in[3];
  const float* WinW = (const float*)d_in[4];
  const float* Winb = (const float*)d_in[5];
  const float* WhW  = (const float*)d_in[6];
  const float* Whb  = (const float*)d_in[7];
  const float* WfcW = (const float*)d_in[8];
  const float* Wfcb = (const float*)d_in[9];
  const float* PcW  = (const float*)d_in[10];
  const float* Pcb  = (const float*)d_in[11];
  const float* PlW  = (const float*)d_in[12];
  const float* Plb  = (const float*)d_in[13];
  const float* H1W  = (const float*)d_in[14];
  const float* H1b  = (const float*)d_in[15];
  const float* H2W  = (const float*)d_in[16];
  const float* H2b  = (const float*)d_in[17];
  const float* H3W  = (const float*)d_in[18];
  const float* H3b  = (const float*)d_in[19];
  float* out = (float*)d_out;

  char* ws = (char*)d_ws;
  __half* s1   = (__half*)(ws + 0);          // [1024][1024][36] f16
  __half* s2   = (__half*)(ws + 75497472);   // [1024][256][36]  f16 (dead after hid16)
  float*  partP = (float*)(ws + 75497472);             // [32][1024][16] f32 (alias s2)
  float*  partS = (float*)(ws + 75497472 + 2097152);   // [18][1024][16] f32 (alias s2)
  __half* s3   = (__half*)(ws + 94371840);   // [1024][64][36] f16
  float*  hb   = (float*)(ws + 99090432);    // [1024][12]
  float*  pb   = (float*)(ws + 99139584);    // [1024][12]
  __half* Bp   = (__half*)(ws + 99188736);   // [11][3][64][8] f16
  float*  b48  = (float*)(ws + 99222528);    // [48]
  __half* Bpriv = (__half*)(ws + 99222720);  // [384][64][8] f16 = 393216
  __half* Bsh   = (__half*)(ws + 99615936);  // [72][64][8]  f16 = 73728
  float*  biasP = (float*)(ws + 99689664);   // [16]
  float*  biasS = (float*)(ws + 99689728);   // [16]
  __half* p1 = s1;                           // reuse after k_hid_mfma<32> consumed s1

  k_prepack<<<1, 256, 0, stream>>>(WhW, Whb, Bp, b48);
  k_prepack_fc<<<64, 256, 0, stream>>>(PlW, Plb, dom, WfcW, Wfcb, Bpriv, Bsh, biasP, biasS);
  k_conv_in<36, false><<<1024, 256, 0, stream>>>(x_s, WinW, Winb, dom, s1);
  k_hid_mfma<32><<<4096, 256, 0, stream>>>(s1, Bp, b48, s2);
  k_hid_mfma<16><<<1024, 256, 0, stream>>>(s2, Bp, b48, s3);
  k_fc_mfma<4><<<dim3(18, 64), 64, 0, stream>>>(s3, Bsh, partS, 2304);
  k_fc_reduce<18, true><<<48, 256, 0, stream>>>(partS, biasS, hb);
  k_conv_in<12, true><<<1024, 256, 0, stream>>>(x_p, PcW, Pcb, dom, p1);
  k_fc_mfma<12><<<dim3(32, 64), 64, 0, stream>>>(p1, Bpriv, partP, 12288);
  k_fc_reduce<32, false><<<48, 256, 0, stream>>>(partP, biasP, pb);
  k_heads<<<4, 256, 0, stream>>>(hb, pb, tt, H1W, H1b, H2W, H2b, H3W, H3b, out);
}

// Round 4
// 409.608 us; speedup vs baseline: 2.6783x; 1.3394x over previous
//
#include <hip/hip_runtime.h>
#include <hip/hip_fp16.h>

typedef _Float16 half8 __attribute__((ext_vector_type(8)));
typedef float floatx4 __attribute__((ext_vector_type(4)));

// ================= conv_in B prepack =================
// Fragment layout [s][nt][lane][8]: n=lane&15, k=q*8+j.
// slice0: tap pi = q*2+(j>>2) in row-major-minus-(2,2) order, c=j&3 (c=3 pad).
// slice1: q==0,j<4 -> tap (2,2), c=j; else zero.
__global__ void k_prepack_cin(const float* __restrict__ Wsh, const float* __restrict__ Ppc,
                              const int* __restrict__ dom,
                              __half* __restrict__ B36, __half* __restrict__ B12) {
  const int tid = threadIdx.x;
  const int dm = dom[0];
  for (int i = tid; i < 3072 + 1024; i += 256) {
    const bool is36 = i < 3072;
    const int ii = is36 ? i : i - 3072;
    const int NT = is36 ? 3 : 1, OCv = is36 ? 36 : 12;
    const int j = ii & 7, lane = (ii >> 3) & 63;
    const int nt = (ii >> 9) % NT, s = ii / (NT * 512);
    const int n = lane & 15, q = lane >> 4, oc = nt * 16 + n;
    int ky, kx, c; bool valid = (oc < OCv);
    if (s == 0) { const int pi = q * 2 + (j >> 2); ky = pi / 3; kx = pi % 3; c = j & 3; }
    else        { ky = 2; kx = 2; c = j; valid = valid && (q == 0 && j < 4); }
    valid = valid && (c < 3);
    float v = 0.f;
    if (valid) {
      const float* W = is36 ? Wsh : (Ppc + (size_t)dm * 12 * 27);
      v = W[((oc * 3 + c) * 3 + ky) * 3 + kx];
    }
    (is36 ? B36 : B12)[ii] = __float2half(v);
  }
}

// ================= MFMA conv_in: 3ch 64x64 conv3x3 + act + 2x2 pool =========
// Block = 8 pre-pool rows of one image; wave = row-pair x 64 wide.
// LDS image [10 rows][68 cols][4ch] f16; A-quad = 2 aligned b64 pixel reads.
template<int OC, bool LEAKY>
__global__ __launch_bounds__(256)
void k_cin_mfma(const float* __restrict__ xin, const __half* __restrict__ Bcin,
                const float* __restrict__ bg, const int* __restrict__ dom,
                __half* __restrict__ outp) {
  constexpr int NT = (OC + 15) / 16;
  __shared__ __align__(16) __half img[10 * 68 * 4 + 8];   // + zero slot
  __shared__ __align__(16) __half ldsB[NT * 2 * 64 * 8];
  const int tid = threadIdx.x;
  const int b  = blockIdx.x >> 3;
  const int br = blockIdx.x & 7;
  const int y0 = br * 8;
  int dm = 0; if (LEAKY) dm = dom[0];
  const float* bsrc = bg + dm * OC;

  for (int i = tid; i < 682; i += 256) ((unsigned long long*)img)[i] = 0ULL;
  {
    const uint4* bs = (const uint4*)Bcin;
    uint4* bd = (uint4*)ldsB;
    for (int i = tid; i < NT * 128; i += 256) bd[i] = bs[i];
  }
  __syncthreads();
  for (int i = tid; i < 480; i += 256) {
    const int r = i / 48, rem = i % 48, c = rem >> 4, xq = rem & 15;
    const int y = y0 - 1 + r;
    if (y >= 0 && y < 64) {
      const float4 f = *(const float4*)(xin + (((size_t)b * 3 + c) * 64 + y) * 64 + xq * 4);
      const int base = (r * 68 + 1 + xq * 4) * 4 + c;
      img[base]      = __float2half(f.x);
      img[base + 4]  = __float2half(f.y);
      img[base + 8]  = __float2half(f.z);
      img[base + 12] = __float2half(f.w);
    }
  }
  __syncthreads();

  const int wave = tid >> 6, lane = tid & 63, ln = lane & 15, q = lane >> 4;
  half8 Bf[2][NT];
#pragma unroll
  for (int s = 0; s < 2; ++s)
#pragma unroll
    for (int nt = 0; nt < NT; ++nt)
      Bf[s][nt] = *(const half8*)&ldsB[((s * NT + nt) * 64 + lane) * 8];

  // quad tap tables (dy,dx relative to center pixel)
  const int dy0_t[4] = {-1, -1, 0, 1}, dx0_t[4] = {-1, 1, 0, -1};
  const int dy1_t[4] = {-1, 0, 0, 1},  dx1_t[4] = {0, -1, 1, 0};
  const int dy0 = dy0_t[q], dx0 = dx0_t[q], dy1 = dy1_t[q], dx1 = dx1_t[q];

  floatx4 acc[2][4][NT];
#pragma unroll
  for (int rb = 0; rb < 2; ++rb)
#pragma unroll
    for (int t = 0; t < 4; ++t)
#pragma unroll
      for (int nt = 0; nt < NT; ++nt) acc[rb][t][nt] = (floatx4){0.f, 0.f, 0.f, 0.f};

#pragma unroll
  for (int rb = 0; rb < 2; ++rb) {
    const int yl = 2 * wave + 1 + rb;
#pragma unroll
    for (int t = 0; t < 4; ++t) {
      const int xc = t * 16 + ln + 1;
      union { half8 h; uint2 u[2]; } A;
      A.u[0] = *(const uint2*)&img[((yl + dy0) * 68 + xc + dx0) * 4];
      A.u[1] = *(const uint2*)&img[((yl + dy1) * 68 + xc + dx1) * 4];
#pragma unroll
      for (int nt = 0; nt < NT; ++nt)
        acc[rb][t][nt] = __builtin_amdgcn_mfma_f32_16x16x32_f16(A.h, Bf[0][nt], acc[rb][t][nt], 0, 0, 0);
      union { half8 h; uint2 u[2]; } A1;
      const int a1off = (q == 0) ? ((yl + 1) * 68 + xc + 1) * 4 : 10 * 68 * 4;
      A1.u[0] = *(const uint2*)&img[a1off];
      A1.u[1] = make_uint2(0u, 0u);
#pragma unroll
      for (int nt = 0; nt < NT; ++nt)
        acc[rb][t][nt] = __builtin_amdgcn_mfma_f32_16x16x32_f16(A1.h, Bf[1][nt], acc[rb][t][nt], 0, 0, 0);
    }
  }

  // epilogue: pool (reg pairs in x, rb pairs in y) + bias + act + store
  const int py = br * 4 + wave;
  float bv[NT];
#pragma unroll
  for (int nt = 0; nt < NT; ++nt) {
    const int oc = nt * 16 + ln;
    bv[nt] = (oc < OC) ? bsrc[oc] : 0.f;
  }
  __half* ob = outp + (size_t)b * 1024 * OC;
#pragma unroll
  for (int t = 0; t < 4; ++t) {
#pragma unroll
    for (int nt = 0; nt < NT; ++nt) {
      const int oc = nt * 16 + ln;
      if (oc < OC) {
        const floatx4 c0 = acc[0][t][nt], c1 = acc[1][t][nt];
        float v0 = fmaxf(fmaxf(c0.x, c0.y), fmaxf(c1.x, c1.y)) + bv[nt];
        float v1 = fmaxf(fmaxf(c0.z, c0.w), fmaxf(c1.z, c1.w)) + bv[nt];
        v0 = LEAKY ? (v0 > 0.f ? v0 : 0.001f * v0) : fmaxf(v0, 0.f);
        v1 = LEAKY ? (v1 > 0.f ? v1 : 0.001f * v1) : fmaxf(v1, 0.f);
        const int px = t * 8 + q * 2;
        ob[(py * 32 + px) * OC + oc]     = __float2half(v0);
        ob[(py * 32 + px + 1) * OC + oc] = __float2half(v1);
      }
    }
  }
}

// ================= hid conv B prepack =================
__global__ void k_prepack(const float* __restrict__ W, const float* __restrict__ b,
                          __half* __restrict__ Bpack, float* __restrict__ bias48) {
  const int tid = threadIdx.x;
  for (int i = tid; i < 11 * 3 * 64 * 8; i += 256) {
    const int j = i & 7, lane = (i >> 3) & 63, nt = (i >> 9) % 3, s = i / 1536;
    const int n = lane & 15, q = lane >> 4;
    const int k = q * 8 + j;
    const int oc = nt * 16 + n;
    int tap, ch; bool valid = true;
    if (s < 9)       { tap = s;      ch = k; }
    else if (s == 9) { tap = k >> 2; ch = 32 + (k & 3); }
    else             { tap = 8;      ch = 32 + k; valid = (k < 4); }
    float v = 0.f;
    if (valid && oc < 36 && ch < 36) v = W[(oc * 36 + ch) * 9 + tap];
    Bpack[i] = __float2half(v);
  }
  if (tid < 48) bias48[tid] = (tid < 36) ? b[tid] : 0.f;
}

// ================= FC weight prepack =================
__global__ void k_prepack_fc(const float* __restrict__ PlW, const float* __restrict__ Plb,
                             const int* __restrict__ dom,
                             const float* __restrict__ WfcW, const float* __restrict__ Wfcb,
                             __half* __restrict__ Bpriv, __half* __restrict__ Bsh,
                             float* __restrict__ bpriv, float* __restrict__ bsh) {
  const int dm = dom[0];
  const int gid = blockIdx.x * 256 + threadIdx.x;
  const int stride = gridDim.x * 256;
  for (int i = gid; i < 384 * 512; i += stride) {
    const int j = i & 7, lane = (i >> 3) & 63, s = i >> 9;
    const int n = lane & 15, q = lane >> 4;
    const int k = s * 32 + q * 8 + j;
    const int pix = k / 12, oc = k - pix * 12;
    float v = 0.f;
    if (n < 12) v = PlW[((size_t)dm * 12 + n) * 12288 + oc * 1024 + pix];
    Bpriv[i] = __float2half(v);
  }
  for (int i = gid; i < 72 * 512; i += stride) {
    const int j = i & 7, lane = (i >> 3) & 63, s = i >> 9;
    const int n = lane & 15, q = lane >> 4;
    const int k = s * 32 + q * 8 + j;
    const int pix = k / 36, oc = k - pix * 36;
    float v = 0.f;
    if (n < 12) v = WfcW[n * 2304 + oc * 64 + pix];
    Bsh[i] = __float2half(v);
  }
  if (gid < 12) { bpriv[gid] = Plb[dm * 12 + gid]; bsh[gid] = Wfcb[gid]; }
}

// ================= MFMA FC =================
template<int SL>
__global__ __launch_bounds__(64)
void k_fc_mfma(const __half* __restrict__ A, const __half* __restrict__ Bf,
               float* __restrict__ part, int Khalves) {
  const int ks = blockIdx.x, mt = blockIdx.y;
  const int lane = threadIdx.x, ln = lane & 15, q = lane >> 4;
  const __half* arow = A + (size_t)(mt * 16 + ln) * Khalves + ks * SL * 32 + q * 8;
  const __half* bptr = Bf + ((size_t)ks * SL * 64 + lane) * 8;
  floatx4 acc = {0.f, 0.f, 0.f, 0.f};
#pragma unroll
  for (int s = 0; s < SL; ++s) {
    const half8 a = *(const half8*)(arow + s * 32);
    const half8 b = *(const half8*)(bptr + s * 512);
    acc = __builtin_amdgcn_mfma_f32_16x16x32_f16(a, b, acc, 0, 0, 0);
  }
  float* pr = part + ((size_t)ks * 1024 + mt * 16) * 16 + ln;
#pragma unroll
  for (int r = 0; r < 4; ++r) pr[(q * 4 + r) * 16] = acc[r];
}

template<int KS, bool RELU>
__global__ __launch_bounds__(256)
void k_fc_reduce(const float* __restrict__ part, const float* __restrict__ bias,
                 float* __restrict__ outv) {
  const int i = blockIdx.x * 256 + threadIdx.x;
  if (i >= 1024 * 12) return;
  const int b = i / 12, hid = i - b * 12;
  float s = bias[hid];
#pragma unroll
  for (int k = 0; k < KS; ++k) s += part[((size_t)k * 1024 + b) * 16 + hid];
  outv[i] = RELU ? fmaxf(s, 0.f) : s;
}

// ================= MFMA implicit-GEMM 36->36 conv3x3 + relu + 2x2 pool ======
template<int IN_S>
__global__ __launch_bounds__(256, 2)
void k_hid_mfma(const __half* __restrict__ sin, const __half* __restrict__ Bpack,
                const float* __restrict__ bias48, __half* __restrict__ sout) {
  constexpr int P = IN_S / 2;
  constexpr int Wd = IN_S + 2;
  constexpr int RPW = (IN_S == 32) ? 2 : 4;
  constexpr int PRB = 4 * RPW;
  constexpr int LROWS = PRB + 2;
  constexpr int HT = IN_S / 16;
  constexpr int BPI = IN_S / PRB;
  constexpr int MT = RPW * HT;
  constexpr int REC = 80;

  __shared__ __align__(16) char ldsA[LROWS * Wd * REC];
  __shared__ __align__(16) char ldsB[11 * 3 * 64 * 16];
  __shared__ float lbias[48];

  const int tid = threadIdx.x;
  const int b  = blockIdx.x / BPI;
  const int br = blockIdx.x % BPI;
  const int y0 = br * PRB;

  {
    const uint4* src = (const uint4*)Bpack;
    uint4* dst = (uint4*)ldsB;
    for (int i = tid; i < 11 * 3 * 64; i += 256) dst[i] = src[i];
    if (tid < 48) lbias[tid] = bias48[tid];
  }
  {
    for (int i = tid; i < LROWS * 2 * 10; i += 256) {
      const int rr = i / 20, rem = i % 20;
      const int pix = (rem >= 10) ? (Wd - 1) : 0;
      *(unsigned long long*)&ldsA[(rr * Wd + pix) * REC + (rem % 10) * 8] = 0ULL;
    }
    const char* gbase = (const char*)(sin + (size_t)b * IN_S * IN_S * 36);
#pragma unroll 1
    for (int rr = 0; rr < LROWS; ++rr) {
      const int iy = y0 - 1 + rr;
      if (iy >= 0 && iy < IN_S) {
        const char* grow = gbase + (size_t)iy * IN_S * 72;
        char* lrow = &ldsA[rr * Wd * REC + REC];
        for (int i = tid; i < IN_S * 9; i += 256) {
          const int pix = i / 9, p = i - pix * 9;
          *(unsigned long long*)&lrow[pix * REC + p * 8] =
              *(const unsigned long long*)&grow[i * 8];
        }
      } else {
        for (int i = tid; i < Wd * 10; i += 256)
          *(unsigned long long*)&ldsA[rr * Wd * REC + i * 8] = 0ULL;
      }
    }
  }
  __syncthreads();

  const int wave = tid >> 6, lane = tid & 63;
  const int ln = lane & 15, q = lane >> 4;

  int baseA[MT];
#pragma unroll
  for (int mt = 0; mt < MT; ++mt) {
    const int r = (IN_S == 32) ? (mt >> 1) : mt;
    const int h = (IN_S == 32) ? (mt & 1) : 0;
    const int pr = wave * RPW + r;
    const int x = h * 16 + ln;
    baseA[mt] = (pr * Wd + x) * REC + q * 16;
  }
  const int tA = 2 * q, tB = 2 * q + 1;
  const int roffA = ((tA / 3) * Wd + (tA % 3)) * REC + 64;
  const int roffB = ((tB / 3) * Wd + (tB % 3)) * REC + 64;
  const int roffC = (2 * Wd + 2) * REC + 64;

  floatx4 acc[MT][3];
#pragma unroll
  for (int mt = 0; mt < MT; ++mt)
#pragma unroll
    for (int nt = 0; nt < 3; ++nt) acc[mt][nt] = (floatx4){0.f, 0.f, 0.f, 0.f};

  const char* lB = ldsB + lane * 16;
#pragma unroll
  for (int s = 0; s < 9; ++s) {
    const int ky = s / 3, kx = s % 3;
    const half8 B0 = *(const half8*)(lB + (s * 3 + 0) * 1024);
    const half8 B1 = *(const half8*)(lB + (s * 3 + 1) * 1024);
    const half8 B2 = *(const half8*)(lB + (s * 3 + 2) * 1024);
#pragma unroll
    for (int mt = 0; mt < MT; ++mt) {
      const half8 A = *(const half8*)(ldsA + baseA[mt] + (ky * Wd + kx) * REC);
      acc[mt][0] = __builtin_amdgcn_mfma_f32_16x16x32_f16(A, B0, acc[mt][0], 0, 0, 0);
      acc[mt][1] = __builtin_amdgcn_mfma_f32_16x16x32_f16(A, B1, acc[mt][1], 0, 0, 0);
      acc[mt][2] = __builtin_amdgcn_mfma_f32_16x16x32_f16(A, B2, acc[mt][2], 0, 0, 0);
    }
  }
#pragma unroll
  for (int s = 9; s <= 10; ++s) {
    const half8 B0 = *(const half8*)(lB + (s * 3 + 0) * 1024);
    const half8 B1 = *(const half8*)(lB + (s * 3 + 1) * 1024);
    const half8 B2 = *(const half8*)(lB + (s * 3 + 2) * 1024);
    const int oA = (s == 9) ? roffA : roffC;
    const int oB = (s == 9) ? roffB : roffC;
#pragma unroll
    for (int mt = 0; mt < MT; ++mt) {
      union { half8 h; uint2 u[2]; } au;
      au.u[0] = *(const uint2*)(ldsA + baseA[mt] + oA);
      au.u[1] = *(const uint2*)(ldsA + baseA[mt] + oB);
      acc[mt][0] = __builtin_amdgcn_mfma_f32_16x16x32_f16(au.h, B0, acc[mt][0], 0, 0, 0);
      acc[mt][1] = __builtin_amdgcn_mfma_f32_16x16x32_f16(au.h, B1, acc[mt][1], 0, 0, 0);
      acc[mt][2] = __builtin_amdgcn_mfma_f32_16x16x32_f16(au.h, B2, acc[mt][2], 0, 0, 0);
    }
  }

  float bv[3];
#pragma unroll
  for (int nt = 0; nt < 3; ++nt) bv[nt] = lbias[nt * 16 + ln];
  __half* outb = sout + (size_t)b * P * P * 36;
#pragma unroll
  for (int pp = 0; pp < RPW / 2; ++pp) {
    const int py = (y0 + wave * RPW) / 2 + pp;
#pragma unroll
    for (int h = 0; h < HT; ++h) {
      const int mtA = (IN_S == 32) ? ((2 * pp) * 2 + h) : (2 * pp);
      const int mtB = (IN_S == 32) ? ((2 * pp + 1) * 2 + h) : (2 * pp + 1);
#pragma unroll
      for (int nt = 0; nt < 3; ++nt) {
        const int oc = nt * 16 + ln;
        if (oc < 36) {
          const floatx4 cA = acc[mtA][nt], cB = acc[mtB][nt];
          const float v0 = fmaxf(fmaxf(fmaxf(cA.x, cA.y), fmaxf(cB.x, cB.y)) + bv[nt], 0.f);
          const float v1 = fmaxf(fmaxf(fmaxf(cA.z, cA.w), fmaxf(cB.z, cB.w)) + bv[nt], 0.f);
          const int px = h * 8 + q * 2;
          outb[(py * P + px) * 36 + oc]     = __float2half(v0);
          outb[(py * P + px + 1) * 36 + oc] = __float2half(v1);
        }
      }
    }
  }
}

// ================= per-sample MoE heads =================
__global__ __launch_bounds__(256)
void k_heads(const float* __restrict__ h, const float* __restrict__ p,
             const int* __restrict__ tt,
             const float* __restrict__ W1, const float* __restrict__ b1,
             const float* __restrict__ W2, const float* __restrict__ b2,
             const float* __restrict__ W3, const float* __restrict__ b3,
             float* __restrict__ out) {
  const int b = blockIdx.x * 256 + threadIdx.x;
  if (b >= 1024) return;
  const int t = tt[b];
  float xv[24];
#pragma unroll
  for (int i = 0; i < 12; ++i) xv[i] = h[b * 12 + i];
#pragma unroll
  for (int i = 0; i < 12; ++i) xv[12 + i] = p[b * 12 + i];
  float h1[28];
  const float* w1 = W1 + t * 28 * 24;
#pragma unroll 1
  for (int i = 0; i < 28; ++i) {
    float s = b1[t * 28 + i];
#pragma unroll
    for (int j = 0; j < 24; ++j) s = fmaf(w1[i * 24 + j], xv[j], s);
    h1[i] = fmaxf(s, 0.f);
  }
  float h2[14];
  const float* w2 = W2 + t * 14 * 28;
#pragma unroll 1
  for (int i = 0; i < 14; ++i) {
    float s = b2[t * 14 + i];
#pragma unroll
    for (int j = 0; j < 28; ++j) s = fmaf(w2[i * 28 + j], h1[j], s);
    h2[i] = fmaxf(s, 0.f);
  }
  const float* w3 = W3 + t * 5 * 14;
#pragma unroll
  for (int i = 0; i < 5; ++i) {
    float s = b3[t * 5 + i];
#pragma unroll
    for (int j = 0; j < 14; ++j) s = fmaf(w3[i * 14 + j], h2[j], s);
    out[b * 5 + i] = s;
  }
}

extern "C" void kernel_launch(void* const* d_in, const int* in_sizes, int n_in,
                              void* d_out, int out_size, void* d_ws, size_t ws_size,
                              hipStream_t stream) {
  const float* x_s  = (const float*)d_in[0];
  const float* x_p  = (const float*)d_in[1];
  const int*   tt   = (const int*)d_in[2];
  const int*   dom  = (const int*)d_in[3];
  const float* WinW = (const float*)d_in[4];
  const float* Winb = (const float*)d_in[5];
  const float* WhW  = (const float*)d_in[6];
  const float* Whb  = (const float*)d_in[7];
  const float* WfcW = (const float*)d_in[8];
  const float* Wfcb = (const float*)d_in[9];
  const float* PcW  = (const float*)d_in[10];
  const float* Pcb  = (const float*)d_in[11];
  const float* PlW  = (const float*)d_in[12];
  const float* Plb  = (const float*)d_in[13];
  const float* H1W  = (const float*)d_in[14];
  const float* H1b  = (const float*)d_in[15];
  const float* H2W  = (const float*)d_in[16];
  const float* H2b  = (const float*)d_in[17];
  const float* H3W  = (const float*)d_in[18];
  const float* H3b  = (const float*)d_in[19];
  float* out = (float*)d_out;

  char* ws = (char*)d_ws;
  __half* s1   = (__half*)(ws + 0);          // [1024][1024][36] f16
  __half* s2   = (__half*)(ws + 75497472);   // [1024][256][36]  f16
  float*  partP = (float*)(ws + 75497472);             // [32][1024][16] (alias s2, post-hid16)
  float*  partS = (float*)(ws + 75497472 + 2097152);   // [18][1024][16] (alias s2)
  __half* s3   = (__half*)(ws + 94371840);   // [1024][64][36] f16
  float*  hb   = (float*)(ws + 99090432);    // [1024][12]
  float*  pb   = (float*)(ws + 99139584);    // [1024][12]
  __half* Bp   = (__half*)(ws + 99188736);   // [11][3][64][8] f16
  float*  b48  = (float*)(ws + 99222528);    // [48]
  __half* Bpriv = (__half*)(ws + 99222720);  // [384][64][8] f16
  __half* Bsh   = (__half*)(ws + 99615936);  // [72][64][8]  f16
  float*  biasP = (float*)(ws + 99689664);   // [16]
  float*  biasS = (float*)(ws + 99689728);   // [16]
  __half* B36   = (__half*)(ws + 99689792);  // [2][3][64][8] = 6144 B
  __half* B12   = (__half*)(ws + 99695936);  // [2][1][64][8] = 2048 B
  __half* p1 = s1;                           // reuse after k_hid_mfma<32> consumed s1

  k_prepack<<<1, 256, 0, stream>>>(WhW, Whb, Bp, b48);
  k_prepack_fc<<<64, 256, 0, stream>>>(PlW, Plb, dom, WfcW, Wfcb, Bpriv, Bsh, biasP, biasS);
  k_prepack_cin<<<1, 256, 0, stream>>>(WinW, PcW, dom, B36, B12);
  k_cin_mfma<36, false><<<8192, 256, 0, stream>>>(x_s, B36, Winb, dom, s1);
  k_hid_mfma<32><<<4096, 256, 0, stream>>>(s1, Bp, b48, s2);
  k_hid_mfma<16><<<1024, 256, 0, stream>>>(s2, Bp, b48, s3);
  k_fc_mfma<4><<<dim3(18, 64), 64, 0, stream>>>(s3, Bsh, partS, 2304);
  k_fc_reduce<18, true><<<48, 256, 0, stream>>>(partS, biasS, hb);
  k_cin_mfma<12, true><<<8192, 256, 0, stream>>>(x_p, B12, Pcb, dom, p1);
  k_fc_mfma<12><<<dim3(32, 64), 64, 0, stream>>>(p1, Bpriv, partP, 12288);
  k_fc_reduce<32, false><<<48, 256, 0, stream>>>(partP, biasP, pb);
  k_heads<<<4, 256, 0, stream>>>(hb, pb, tt, H1W, H1b, H2W, H2b, H3W, H3b, out);
}

// Round 5
// 360.762 us; speedup vs baseline: 3.0409x; 1.1354x over previous
//
#include <hip/hip_runtime.h>
#include <hip/hip_fp16.h>

typedef _Float16 half8 __attribute__((ext_vector_type(8)));
typedef float floatx4 __attribute__((ext_vector_type(4)));

// ================= conv_in B prepack =================
__global__ void k_prepack_cin(const float* __restrict__ Wsh, const float* __restrict__ Ppc,
                              const int* __restrict__ dom,
                              __half* __restrict__ B36, __half* __restrict__ B12) {
  const int tid = threadIdx.x;
  const int dm = dom[0];
  for (int i = tid; i < 3072 + 1024; i += 256) {
    const bool is36 = i < 3072;
    const int ii = is36 ? i : i - 3072;
    const int NT = is36 ? 3 : 1, OCv = is36 ? 36 : 12;
    const int j = ii & 7, lane = (ii >> 3) & 63;
    const int nt = (ii >> 9) % NT, s = ii / (NT * 512);
    const int n = lane & 15, q = lane >> 4, oc = nt * 16 + n;
    int ky, kx, c; bool valid = (oc < OCv);
    if (s == 0) { const int pi = q * 2 + (j >> 2); ky = pi / 3; kx = pi % 3; c = j & 3; }
    else        { ky = 2; kx = 2; c = j; valid = valid && (q == 0 && j < 4); }
    valid = valid && (c < 3);
    float v = 0.f;
    if (valid) {
      const float* W = is36 ? Wsh : (Ppc + (size_t)dm * 12 * 27);
      v = W[((oc * 3 + c) * 3 + ky) * 3 + kx];
    }
    (is36 ? B36 : B12)[ii] = __float2half(v);
  }
}

// ================= MFMA conv_in: 3ch 64x64 conv3x3 + act + 2x2 pool =========
// Two-phase staging: all global loads in flight, then LDS writes, one barrier.
template<int OC, bool LEAKY>
__global__ __launch_bounds__(256)
void k_cin_mfma(const float* __restrict__ xin, const __half* __restrict__ Bcin,
                const float* __restrict__ bg, const int* __restrict__ dom,
                __half* __restrict__ outp) {
  constexpr int NT = (OC + 15) / 16;
  constexpr int PU = 640;                 // 10 rows x 64 px
  constexpr int NU = 3;                   // ceil(640/256)
  constexpr int NBW = (NT * 128 + 255) / 256;
  __shared__ __align__(16) __half img[10 * 68 * 4 + 8];
  __shared__ __align__(16) __half ldsB[NT * 2 * 64 * 8];
  const int tid = threadIdx.x;
  const int b  = blockIdx.x >> 3;
  const int br = blockIdx.x & 7;
  const int y0 = br * 8;
  int dm = 0; if (LEAKY) dm = dom[0];
  const float* bsrc = bg + dm * OC;

  // ---- phase 1: global loads into registers ----
  float c0[NU], c1[NU], c2[NU];
#pragma unroll
  for (int u = 0; u < NU; ++u) {
    const int i = tid + u * 256;
    float v0 = 0.f, v1 = 0.f, v2 = 0.f;
    if (i < PU) {
      const int r = i >> 6, px = i & 63;
      const int y = y0 - 1 + r;
      if (y >= 0 && y < 64) {
        const float* p0 = xin + (((size_t)b * 3) * 64 + y) * 64 + px;
        v0 = p0[0]; v1 = p0[4096]; v2 = p0[8192];
      }
    }
    c0[u] = v0; c1[u] = v1; c2[u] = v2;
  }
  uint4 bregs[NBW];
  {
    const uint4* bs = (const uint4*)Bcin;
#pragma unroll
    for (int u = 0; u < NBW; ++u) {
      const int i = tid + u * 256;
      bregs[u] = (i < NT * 128) ? bs[i] : make_uint4(0, 0, 0, 0);
    }
  }
  // ---- phase 2: LDS writes ----
  if (tid < 22) {
    int addr;
    if (tid < 10) addr = (tid * 68) * 4;
    else if (tid < 20) addr = ((tid - 10) * 68 + 65) * 4;
    else addr = 10 * 68 * 4 + (tid - 20) * 4;
    *(unsigned long long*)&img[addr] = 0ULL;
  }
#pragma unroll
  for (int u = 0; u < NBW; ++u) {
    const int i = tid + u * 256;
    if (i < NT * 128) ((uint4*)ldsB)[i] = bregs[u];
  }
#pragma unroll
  for (int u = 0; u < NU; ++u) {
    const int i = tid + u * 256;
    if (i < PU) {
      const int r = i >> 6, px = i & 63;
      __half2 lo = __floats2half2_rn(c0[u], c1[u]);
      __half2 hi = __floats2half2_rn(c2[u], 0.f);
      *(uint2*)&img[(r * 68 + 1 + px) * 4] =
          make_uint2(*(unsigned int*)&lo, *(unsigned int*)&hi);
    }
  }
  __syncthreads();

  const int wave = tid >> 6, lane = tid & 63, ln = lane & 15, q = lane >> 4;
  half8 Bf[2][NT];
#pragma unroll
  for (int s = 0; s < 2; ++s)
#pragma unroll
    for (int nt = 0; nt < NT; ++nt)
      Bf[s][nt] = *(const half8*)&ldsB[((s * NT + nt) * 64 + lane) * 8];

  const int dy0_t[4] = {-1, -1, 0, 1}, dx0_t[4] = {-1, 1, 0, -1};
  const int dy1_t[4] = {-1, 0, 0, 1},  dx1_t[4] = {0, -1, 1, 0};
  const int dy0 = dy0_t[q], dx0 = dx0_t[q], dy1 = dy1_t[q], dx1 = dx1_t[q];

  floatx4 acc[2][4][NT];
#pragma unroll
  for (int rb = 0; rb < 2; ++rb)
#pragma unroll
    for (int t = 0; t < 4; ++t)
#pragma unroll
      for (int nt = 0; nt < NT; ++nt) acc[rb][t][nt] = (floatx4){0.f, 0.f, 0.f, 0.f};

#pragma unroll
  for (int rb = 0; rb < 2; ++rb) {
    const int yl = 2 * wave + 1 + rb;
#pragma unroll
    for (int t = 0; t < 4; ++t) {
      const int xc = t * 16 + ln + 1;
      union { half8 h; uint2 u[2]; } A;
      A.u[0] = *(const uint2*)&img[((yl + dy0) * 68 + xc + dx0) * 4];
      A.u[1] = *(const uint2*)&img[((yl + dy1) * 68 + xc + dx1) * 4];
#pragma unroll
      for (int nt = 0; nt < NT; ++nt)
        acc[rb][t][nt] = __builtin_amdgcn_mfma_f32_16x16x32_f16(A.h, Bf[0][nt], acc[rb][t][nt], 0, 0, 0);
      union { half8 h; uint2 u[2]; } A1;
      const int a1off = (q == 0) ? ((yl + 1) * 68 + xc + 1) * 4 : 10 * 68 * 4;
      A1.u[0] = *(const uint2*)&img[a1off];
      A1.u[1] = make_uint2(0u, 0u);
#pragma unroll
      for (int nt = 0; nt < NT; ++nt)
        acc[rb][t][nt] = __builtin_amdgcn_mfma_f32_16x16x32_f16(A1.h, Bf[1][nt], acc[rb][t][nt], 0, 0, 0);
    }
  }

  const int py = br * 4 + wave;
  float bv[NT];
#pragma unroll
  for (int nt = 0; nt < NT; ++nt) {
    const int oc = nt * 16 + ln;
    bv[nt] = (oc < OC) ? bsrc[oc] : 0.f;
  }
  __half* ob = outp + (size_t)b * 1024 * OC;
#pragma unroll
  for (int t = 0; t < 4; ++t) {
#pragma unroll
    for (int nt = 0; nt < NT; ++nt) {
      const int oc = nt * 16 + ln;
      if (oc < OC) {
        const floatx4 cc0 = acc[0][t][nt], cc1 = acc[1][t][nt];
        float v0 = fmaxf(fmaxf(cc0.x, cc0.y), fmaxf(cc1.x, cc1.y)) + bv[nt];
        float v1 = fmaxf(fmaxf(cc0.z, cc0.w), fmaxf(cc1.z, cc1.w)) + bv[nt];
        v0 = LEAKY ? (v0 > 0.f ? v0 : 0.001f * v0) : fmaxf(v0, 0.f);
        v1 = LEAKY ? (v1 > 0.f ? v1 : 0.001f * v1) : fmaxf(v1, 0.f);
        const int px = t * 8 + q * 2;
        ob[(py * 32 + px) * OC + oc]     = __float2half(v0);
        ob[(py * 32 + px + 1) * OC + oc] = __float2half(v1);
      }
    }
  }
}

// ================= hid conv B prepack =================
__global__ void k_prepack(const float* __restrict__ W, const float* __restrict__ b,
                          __half* __restrict__ Bpack, float* __restrict__ bias48) {
  const int tid = threadIdx.x;
  for (int i = tid; i < 11 * 3 * 64 * 8; i += 256) {
    const int j = i & 7, lane = (i >> 3) & 63, nt = (i >> 9) % 3, s = i / 1536;
    const int n = lane & 15, q = lane >> 4;
    const int k = q * 8 + j;
    const int oc = nt * 16 + n;
    int tap, ch; bool valid = true;
    if (s < 9)       { tap = s;      ch = k; }
    else if (s == 9) { tap = k >> 2; ch = 32 + (k & 3); }
    else             { tap = 8;      ch = 32 + k; valid = (k < 4); }
    float v = 0.f;
    if (valid && oc < 36 && ch < 36) v = W[(oc * 36 + ch) * 9 + tap];
    Bpack[i] = __float2half(v);
  }
  if (tid < 48) bias48[tid] = (tid < 36) ? b[tid] : 0.f;
}

// ================= FC weight prepack =================
__global__ void k_prepack_fc(const float* __restrict__ PlW, const float* __restrict__ Plb,
                             const int* __restrict__ dom,
                             const float* __restrict__ WfcW, const float* __restrict__ Wfcb,
                             __half* __restrict__ Bpriv, __half* __restrict__ Bsh,
                             float* __restrict__ bpriv, float* __restrict__ bsh) {
  const int dm = dom[0];
  const int gid = blockIdx.x * 256 + threadIdx.x;
  const int stride = gridDim.x * 256;
  for (int i = gid; i < 384 * 512; i += stride) {
    const int j = i & 7, lane = (i >> 3) & 63, s = i >> 9;
    const int n = lane & 15, q = lane >> 4;
    const int k = s * 32 + q * 8 + j;
    const int pix = k / 12, oc = k - pix * 12;
    float v = 0.f;
    if (n < 12) v = PlW[((size_t)dm * 12 + n) * 12288 + oc * 1024 + pix];
    Bpriv[i] = __float2half(v);
  }
  for (int i = gid; i < 72 * 512; i += stride) {
    const int j = i & 7, lane = (i >> 3) & 63, s = i >> 9;
    const int n = lane & 15, q = lane >> 4;
    const int k = s * 32 + q * 8 + j;
    const int pix = k / 36, oc = k - pix * 36;
    float v = 0.f;
    if (n < 12) v = WfcW[n * 2304 + oc * 64 + pix];
    Bsh[i] = __float2half(v);
  }
  if (gid < 12) { bpriv[gid] = Plb[dm * 12 + gid]; bsh[gid] = Wfcb[gid]; }
}

// ================= MFMA FC =================
template<int SL>
__global__ __launch_bounds__(64)
void k_fc_mfma(const __half* __restrict__ A, const __half* __restrict__ Bf,
               float* __restrict__ part, int Khalves) {
  const int ks = blockIdx.x, mt = blockIdx.y;
  const int lane = threadIdx.x, ln = lane & 15, q = lane >> 4;
  const __half* arow = A + (size_t)(mt * 16 + ln) * Khalves + ks * SL * 32 + q * 8;
  const __half* bptr = Bf + ((size_t)ks * SL * 64 + lane) * 8;
  floatx4 acc = {0.f, 0.f, 0.f, 0.f};
#pragma unroll
  for (int s = 0; s < SL; ++s) {
    const half8 a = *(const half8*)(arow + s * 32);
    const half8 b = *(const half8*)(bptr + s * 512);
    acc = __builtin_amdgcn_mfma_f32_16x16x32_f16(a, b, acc, 0, 0, 0);
  }
  float* pr = part + ((size_t)ks * 1024 + mt * 16) * 16 + ln;
#pragma unroll
  for (int r = 0; r < 4; ++r) pr[(q * 4 + r) * 16] = acc[r];
}

template<int KS, bool RELU>
__global__ __launch_bounds__(256)
void k_fc_reduce(const float* __restrict__ part, const float* __restrict__ bias,
                 float* __restrict__ outv) {
  const int i = blockIdx.x * 256 + threadIdx.x;
  if (i >= 1024 * 12) return;
  const int b = i / 12, hid = i - b * 12;
  float s = bias[hid];
#pragma unroll
  for (int k = 0; k < KS; ++k) s += part[((size_t)k * 1024 + b) * 16 + hid];
  outv[i] = RELU ? fmaxf(s, 0.f) : s;
}

// ================= MFMA implicit-GEMM 36->36 conv3x3 + relu + 2x2 pool ======
// Two-phase staging: A-tile as 16B units (part 4 overlap-reads into pad),
// B-tile + bias in the same load flight; single vmcnt drain + one barrier.
template<int IN_S>
__global__ __launch_bounds__(256, 2)
void k_hid_mfma(const __half* __restrict__ sin, const __half* __restrict__ Bpack,
                const float* __restrict__ bias48, __half* __restrict__ sout) {
  constexpr int P = IN_S / 2;
  constexpr int Wd = IN_S + 2;
  constexpr int RPW = (IN_S == 32) ? 2 : 4;
  constexpr int PRB = 4 * RPW;
  constexpr int LROWS = PRB + 2;
  constexpr int HT = IN_S / 16;
  constexpr int BPI = IN_S / PRB;
  constexpr int MT = RPW * HT;
  constexpr int REC = 80;
  constexpr int UNITS = LROWS * IN_S * 5;         // 16B units in A tile
  constexpr int NU = (UNITS + 255) / 256;
  constexpr int NB = (2112 + 255) / 256;          // B tile 16B units

  __shared__ __align__(16) char ldsA[LROWS * Wd * REC];
  __shared__ __align__(16) char ldsB[11 * 3 * 64 * 16];
  __shared__ float lbias[48];

  const int tid = threadIdx.x;
  const int b  = blockIdx.x / BPI;
  const int br = blockIdx.x % BPI;
  const int y0 = br * PRB;

  // ---- phase 1: all global loads into registers ----
  uint4 aregs[NU];
  {
    const char* gb = (const char*)(sin + (size_t)b * IN_S * IN_S * 36);
#pragma unroll
    for (int u = 0; u < NU; ++u) {
      const int i = tid + u * 256;
      uint4 v = make_uint4(0, 0, 0, 0);
      if (i < UNITS) {
        const int r = i / (IN_S * 5);
        const int rem = i - r * (IN_S * 5);
        const int pix = rem / 5, part = rem - pix * 5;
        const int iy = y0 - 1 + r;
        if (iy >= 0 && iy < IN_S)
          v = *(const uint4*)(gb + ((size_t)iy * IN_S + pix) * 72 + part * 16);
      }
      aregs[u] = v;
    }
  }
  uint4 bregs[NB];
  {
    const uint4* bs = (const uint4*)Bpack;
#pragma unroll
    for (int u = 0; u < NB; ++u) {
      const int i = tid + u * 256;
      bregs[u] = (i < 2112) ? bs[i] : make_uint4(0, 0, 0, 0);
    }
  }
  const float biasreg = (tid < 48) ? bias48[tid] : 0.f;

  // ---- phase 2: LDS writes ----
#pragma unroll
  for (int u = 0; u < NB; ++u) {
    const int i = tid + u * 256;
    if (i < 2112) ((uint4*)ldsB)[i] = bregs[u];
  }
  if (tid < 48) lbias[tid] = biasreg;
  for (int i = tid; i < LROWS * 10; i += 256) {     // halo columns
    const int r = i / 10, rem = i % 10;
    const int pix = (rem >= 5) ? (Wd - 1) : 0;
    *(uint4*)&ldsA[(r * Wd + pix) * REC + (rem % 5) * 16] = make_uint4(0, 0, 0, 0);
  }
#pragma unroll
  for (int u = 0; u < NU; ++u) {
    const int i = tid + u * 256;
    if (i < UNITS) {
      const int r = i / (IN_S * 5);
      const int rem = i - r * (IN_S * 5);
      const int pix = rem / 5, part = rem - pix * 5;
      *(uint4*)&ldsA[(r * Wd + 1 + pix) * REC + part * 16] = aregs[u];
    }
  }
  __syncthreads();

  const int wave = tid >> 6, lane = tid & 63;
  const int ln = lane & 15, q = lane >> 4;

  int baseA[MT];
#pragma unroll
  for (int mt = 0; mt < MT; ++mt) {
    const int r = (IN_S == 32) ? (mt >> 1) : mt;
    const int h = (IN_S == 32) ? (mt & 1) : 0;
    const int pr = wave * RPW + r;
    const int x = h * 16 + ln;
    baseA[mt] = (pr * Wd + x) * REC + q * 16;
  }
  const int tA = 2 * q, tB = 2 * q + 1;
  const int roffA = ((tA / 3) * Wd + (tA % 3)) * REC + 64;
  const int roffB = ((tB / 3) * Wd + (tB % 3)) * REC + 64;
  const int roffC = (2 * Wd + 2) * REC + 64;

  floatx4 acc[MT][3];
#pragma unroll
  for (int mt = 0; mt < MT; ++mt)
#pragma unroll
    for (int nt = 0; nt < 3; ++nt) acc[mt][nt] = (floatx4){0.f, 0.f, 0.f, 0.f};

  const char* lB = ldsB + lane * 16;
#pragma unroll
  for (int s = 0; s < 9; ++s) {
    const int ky = s / 3, kx = s % 3;
    const half8 B0 = *(const half8*)(lB + (s * 3 + 0) * 1024);
    const half8 B1 = *(const half8*)(lB + (s * 3 + 1) * 1024);
    const half8 B2 = *(const half8*)(lB + (s * 3 + 2) * 1024);
#pragma unroll
    for (int mt = 0; mt < MT; ++mt) {
      const half8 A = *(const half8*)(ldsA + baseA[mt] + (ky * Wd + kx) * REC);
      acc[mt][0] = __builtin_amdgcn_mfma_f32_16x16x32_f16(A, B0, acc[mt][0], 0, 0, 0);
      acc[mt][1] = __builtin_amdgcn_mfma_f32_16x16x32_f16(A, B1, acc[mt][1], 0, 0, 0);
      acc[mt][2] = __builtin_amdgcn_mfma_f32_16x16x32_f16(A, B2, acc[mt][2], 0, 0, 0);
    }
  }
#pragma unroll
  for (int s = 9; s <= 10; ++s) {
    const half8 B0 = *(const half8*)(lB + (s * 3 + 0) * 1024);
    const half8 B1 = *(const half8*)(lB + (s * 3 + 1) * 1024);
    const half8 B2 = *(const half8*)(lB + (s * 3 + 2) * 1024);
    const int oA = (s == 9) ? roffA : roffC;
    const int oB = (s == 9) ? roffB : roffC;
#pragma unroll
    for (int mt = 0; mt < MT; ++mt) {
      union { half8 h; uint2 u[2]; } au;
      au.u[0] = *(const uint2*)(ldsA + baseA[mt] + oA);
      au.u[1] = *(const uint2*)(ldsA + baseA[mt] + oB);
      acc[mt][0] = __builtin_amdgcn_mfma_f32_16x16x32_f16(au.h, B0, acc[mt][0], 0, 0, 0);
      acc[mt][1] = __builtin_amdgcn_mfma_f32_16x16x32_f16(au.h, B1, acc[mt][1], 0, 0, 0);
      acc[mt][2] = __builtin_amdgcn_mfma_f32_16x16x32_f16(au.h, B2, acc[mt][2], 0, 0, 0);
    }
  }

  float bv[3];
#pragma unroll
  for (int nt = 0; nt < 3; ++nt) bv[nt] = lbias[nt * 16 + ln];
  __half* outb = sout + (size_t)b * P * P * 36;
#pragma unroll
  for (int pp = 0; pp < RPW / 2; ++pp) {
    const int py = (y0 + wave * RPW) / 2 + pp;
#pragma unroll
    for (int h = 0; h < HT; ++h) {
      const int mtA = (IN_S == 32) ? ((2 * pp) * 2 + h) : (2 * pp);
      const int mtB = (IN_S == 32) ? ((2 * pp + 1) * 2 + h) : (2 * pp + 1);
#pragma unroll
      for (int nt = 0; nt < 3; ++nt) {
        const int oc = nt * 16 + ln;
        if (oc < 36) {
          const floatx4 cA = acc[mtA][nt], cB = acc[mtB][nt];
          const float v0 = fmaxf(fmaxf(fmaxf(cA.x, cA.y), fmaxf(cB.x, cB.y)) + bv[nt], 0.f);
          const float v1 = fmaxf(fmaxf(fmaxf(cA.z, cA.w), fmaxf(cB.z, cB.w)) + bv[nt], 0.f);
          const int px = h * 8 + q * 2;
          outb[(py * P + px) * 36 + oc]     = __float2half(v0);
          outb[(py * P + px + 1) * 36 + oc] = __float2half(v1);
        }
      }
    }
  }
}

// ================= per-sample MoE heads =================
__global__ __launch_bounds__(256)
void k_heads(const float* __restrict__ h, const float* __restrict__ p,
             const int* __restrict__ tt,
             const float* __restrict__ W1, const float* __restrict__ b1,
             const float* __restrict__ W2, const float* __restrict__ b2,
             const float* __restrict__ W3, const float* __restrict__ b3,
             float* __restrict__ out) {
  const int b = blockIdx.x * 256 + threadIdx.x;
  if (b >= 1024) return;
  const int t = tt[b];
  float xv[24];
#pragma unroll
  for (int i = 0; i < 12; ++i) xv[i] = h[b * 12 + i];
#pragma unroll
  for (int i = 0; i < 12; ++i) xv[12 + i] = p[b * 12 + i];
  float h1[28];
  const float* w1 = W1 + t * 28 * 24;
#pragma unroll 1
  for (int i = 0; i < 28; ++i) {
    float s = b1[t * 28 + i];
#pragma unroll
    for (int j = 0; j < 24; ++j) s = fmaf(w1[i * 24 + j], xv[j], s);
    h1[i] = fmaxf(s, 0.f);
  }
  float h2[14];
  const float* w2 = W2 + t * 14 * 28;
#pragma unroll 1
  for (int i = 0; i < 14; ++i) {
    float s = b2[t * 14 + i];
#pragma unroll
    for (int j = 0; j < 28; ++j) s = fmaf(w2[i * 28 + j], h1[j], s);
    h2[i] = fmaxf(s, 0.f);
  }
  const float* w3 = W3 + t * 5 * 14;
#pragma unroll
  for (int i = 0; i < 5; ++i) {
    float s = b3[t * 5 + i];
#pragma unroll
    for (int j = 0; j < 14; ++j) s = fmaf(w3[i * 14 + j], h2[j], s);
    out[b * 5 + i] = s;
  }
}

extern "C" void kernel_launch(void* const* d_in, const int* in_sizes, int n_in,
                              void* d_out, int out_size, void* d_ws, size_t ws_size,
                              hipStream_t stream) {
  const float* x_s  = (const float*)d_in[0];
  const float* x_p  = (const float*)d_in[1];
  const int*   tt   = (const int*)d_in[2];
  const int*   dom  = (const int*)d_in[3];
  const float* WinW = (const float*)d_in[4];
  const float* Winb = (const float*)d_in[5];
  const float* WhW  = (const float*)d_in[6];
  const float* Whb  = (const float*)d_in[7];
  const float* WfcW = (const float*)d_in[8];
  const float* Wfcb = (const float*)d_in[9];
  const float* PcW  = (const float*)d_in[10];
  const float* Pcb  = (const float*)d_in[11];
  const float* PlW  = (const float*)d_in[12];
  const float* Plb  = (const float*)d_in[13];
  const float* H1W  = (const float*)d_in[14];
  const float* H1b  = (const float*)d_in[15];
  const float* H2W  = (const float*)d_in[16];
  const float* H2b  = (const float*)d_in[17];
  const float* H3W  = (const float*)d_in[18];
  const float* H3b  = (const float*)d_in[19];
  float* out = (float*)d_out;

  char* ws = (char*)d_ws;
  __half* s1   = (__half*)(ws + 0);          // [1024][1024][36] f16
  __half* s2   = (__half*)(ws + 75497472);   // [1024][256][36]  f16
  float*  partP = (float*)(ws + 75497472);             // [32][1024][16] (alias s2, post-hid16)
  float*  partS = (float*)(ws + 75497472 + 2097152);   // [18][1024][16] (alias s2)
  __half* s3   = (__half*)(ws + 94371840);   // [1024][64][36] f16
  float*  hb   = (float*)(ws + 99090432);    // [1024][12]
  float*  pb   = (float*)(ws + 99139584);    // [1024][12]
  __half* Bp   = (__half*)(ws + 99188736);   // [11][3][64][8] f16
  float*  b48  = (float*)(ws + 99222528);    // [48]
  __half* Bpriv = (__half*)(ws + 99222720);  // [384][64][8] f16
  __half* Bsh   = (__half*)(ws + 99615936);  // [72][64][8]  f16
  float*  biasP = (float*)(ws + 99689664);   // [16]
  float*  biasS = (float*)(ws + 99689728);   // [16]
  __half* B36   = (__half*)(ws + 99689792);  // [2][3][64][8]
  __half* B12   = (__half*)(ws + 99695936);  // [2][1][64][8]
  __half* p1 = s1;                           // reuse after k_hid_mfma<32> consumed s1

  k_prepack<<<1, 256, 0, stream>>>(WhW, Whb, Bp, b48);
  k_prepack_fc<<<64, 256, 0, stream>>>(PlW, Plb, dom, WfcW, Wfcb, Bpriv, Bsh, biasP, biasS);
  k_prepack_cin<<<1, 256, 0, stream>>>(WinW, PcW, dom, B36, B12);
  k_cin_mfma<36, false><<<8192, 256, 0, stream>>>(x_s, B36, Winb, dom, s1);
  k_hid_mfma<32><<<4096, 256, 0, stream>>>(s1, Bp, b48, s2);
  k_hid_mfma<16><<<1024, 256, 0, stream>>>(s2, Bp, b48, s3);
  k_fc_mfma<4><<<dim3(18, 64), 64, 0, stream>>>(s3, Bsh, partS, 2304);
  k_fc_reduce<18, true><<<48, 256, 0, stream>>>(partS, biasS, hb);
  k_cin_mfma<12, true><<<8192, 256, 0, stream>>>(x_p, B12, Pcb, dom, p1);
  k_fc_mfma<12><<<dim3(32, 64), 64, 0, stream>>>(p1, Bpriv, partP, 12288);
  k_fc_reduce<32, false><<<48, 256, 0, stream>>>(partP, biasP, pb);
  k_heads<<<4, 256, 0, stream>>>(hb, pb, tt, H1W, H1b, H2W, H2b, H3W, H3b, out);
}

// Round 6
// 321.931 us; speedup vs baseline: 3.4077x; 1.1206x over previous
//
#include <hip/hip_runtime.h>
#include <hip/hip_fp16.h>

typedef _Float16 half8 __attribute__((ext_vector_type(8)));
typedef float floatx4 __attribute__((ext_vector_type(4)));

// ---------------- prepack: hid Bfrag + bias48 + conv_in Bfrags --------------
__global__ void k_prepack_small(const float* __restrict__ WhW, const float* __restrict__ Whb,
                                const float* __restrict__ WinW, const float* __restrict__ PcW,
                                const int* __restrict__ dom,
                                __half* __restrict__ Bpack, float* __restrict__ bias48,
                                __half* __restrict__ B36, __half* __restrict__ B12) {
  const int tid = threadIdx.x;
  const int dm = dom[0];
  // hid conv B: [11 slices][3 nt][64 lanes][8]
  for (int i = tid; i < 11 * 3 * 64 * 8; i += 256) {
    const int j = i & 7, lane = (i >> 3) & 63, nt = (i >> 9) % 3, s = i / 1536;
    const int n = lane & 15, q = lane >> 4;
    const int k = q * 8 + j;
    const int oc = nt * 16 + n;
    int tap, ch; bool valid = true;
    if (s < 9)       { tap = s;      ch = k; }
    else if (s == 9) { tap = k >> 2; ch = 32 + (k & 3); }
    else             { tap = 8;      ch = 32 + k; valid = (k < 4); }
    float v = 0.f;
    if (valid && oc < 36 && ch < 36) v = WhW[(oc * 36 + ch) * 9 + tap];
    Bpack[i] = __float2half(v);
  }
  if (tid < 48) bias48[tid] = (tid < 36) ? Whb[tid] : 0.f;
  // conv_in B frags: [2 slices][NT][64][8]
  for (int i = tid; i < 3072 + 1024; i += 256) {
    const bool is36 = i < 3072;
    const int ii = is36 ? i : i - 3072;
    const int NT = is36 ? 3 : 1, OCv = is36 ? 36 : 12;
    const int j = ii & 7, lane = (ii >> 3) & 63;
    const int nt = (ii >> 9) % NT, s = ii / (NT * 512);
    const int n = lane & 15, q = lane >> 4, oc = nt * 16 + n;
    int ky, kx, c; bool valid = (oc < OCv);
    if (s == 0) { const int pi = q * 2 + (j >> 2); ky = pi / 3; kx = pi % 3; c = j & 3; }
    else        { ky = 2; kx = 2; c = j; valid = valid && (q == 0 && j < 4); }
    valid = valid && (c < 3);
    float v = 0.f;
    if (valid) {
      const float* W = is36 ? WinW : (PcW + (size_t)dm * 12 * 27);
      v = W[((oc * 3 + c) * 3 + ky) * 3 + kx];
    }
    (is36 ? B36 : B12)[ii] = __float2half(v);
  }
}

// ---------------- prepack: plain f16 FC weights in activation-storage order -
// Wpp[hid][k], k = pix*12+oc  (ref e = oc*1024+pix)
// Wshp[hid][k], k = p*36+oc   (ref e = oc*64+p)
__global__ void k_prepack_fcp(const float* __restrict__ PlW, const int* __restrict__ dom,
                              const float* __restrict__ WfcW,
                              __half* __restrict__ Wpp, __half* __restrict__ Wshp) {
  const int dm = dom[0];
  const int gid = blockIdx.x * 256 + threadIdx.x;
  const int stride = gridDim.x * 256;
  for (int i = gid; i < 147456; i += stride) {
    const int hid = i / 12288, k = i - hid * 12288;
    const int oc = k % 12, pix = k / 12;
    Wpp[i] = __float2half(PlW[((size_t)dm * 12 + hid) * 12288 + oc * 1024 + pix]);
  }
  for (int i = gid; i < 27648; i += stride) {
    const int hid = i / 2304, k = i - hid * 2304;
    const int oc = k % 36, p = k / 36;
    Wshp[i] = __float2half(WfcW[hid * 2304 + oc * 64 + p]);
  }
}

// ---------------- fused private branch: conv(3->12,leaky)+pool + FC ---------
// One block per image. img LDS [66][68][4ch] f16; ptile [1024][12] f16.
__global__ __launch_bounds__(256)
void k_priv(const float* __restrict__ xin, const __half* __restrict__ B12,
            const float* __restrict__ Pcb, const int* __restrict__ dom,
            const __half* __restrict__ Wpp, const float* __restrict__ Plb,
            float* __restrict__ pb) {
  __shared__ __align__(16) __half img[66 * 68 * 4];
  __shared__ __align__(16) __half ptile[1024 * 12];
  __shared__ float red[4][12];
  const int tid = threadIdx.x, b = blockIdx.x;
  const int lane = tid & 63, wave = tid >> 6, ln = lane & 15, q = lane >> 4;
  const int dm = dom[0];

  // phase 1: all global loads in flight
  float c0[16], c1[16], c2[16];
#pragma unroll
  for (int u = 0; u < 16; ++u) {
    const int i = tid + u * 256;
    const int y = i >> 6, px = i & 63;
    const float* p0 = xin + (size_t)b * 12288 + y * 64 + px;
    c0[u] = p0[0]; c1[u] = p0[4096]; c2[u] = p0[8192];
  }
  const half8 Bf0 = *(const half8*)(B12 + lane * 8);
  const half8 Bf1 = *(const half8*)(B12 + (64 + lane) * 8);
  const float bv = (ln < 12) ? Pcb[dm * 12 + ln] : 0.f;
  // phase 2: halo zero + packed LDS writes
  for (int i = tid; i < 264; i += 256) {
    int hidx;
    if (i < 136) { const int r = (i < 68) ? 0 : 65; hidx = (r * 68 + (i % 68)) * 4; }
    else { const int j = i - 136; const int r = 1 + (j & 63); hidx = (r * 68 + ((j < 64) ? 0 : 65)) * 4; }
    *(unsigned long long*)&img[hidx] = 0ULL;
  }
#pragma unroll
  for (int u = 0; u < 16; ++u) {
    const int i = tid + u * 256;
    const int y = i >> 6, px = i & 63;
    __half2 lo = __floats2half2_rn(c0[u], c1[u]);
    __half2 hi = __floats2half2_rn(c2[u], 0.f);
    *(uint2*)&img[((y + 1) * 68 + px + 1) * 4] =
        make_uint2(*(unsigned int*)&lo, *(unsigned int*)&hi);
  }
  __syncthreads();

  const int dy0_t[4] = {-1, -1, 0, 1}, dx0_t[4] = {-1, 1, 0, -1};
  const int dy1_t[4] = {-1, 0, 0, 1},  dx1_t[4] = {0, -1, 1, 0};
  const int dy0 = dy0_t[q], dx0 = dx0_t[q], dy1 = dy1_t[q], dx1 = dx1_t[q];
  const int zoff = (65 * 68 + 66) * 4;

#pragma unroll 1
  for (int kk = 0; kk < 8; ++kk) {
    const int pr = 4 * kk + wave;          // pooled row 0..31
    floatx4 acc[2][4];
#pragma unroll
    for (int rb = 0; rb < 2; ++rb)
#pragma unroll
      for (int t = 0; t < 4; ++t) acc[rb][t] = (floatx4){0.f, 0.f, 0.f, 0.f};
#pragma unroll
    for (int rb = 0; rb < 2; ++rb) {
      const int yl = 2 * pr + rb + 1;
#pragma unroll
      for (int t = 0; t < 4; ++t) {
        const int xc = t * 16 + ln + 1;
        union { half8 h; uint2 u[2]; } A;
        A.u[0] = *(const uint2*)&img[((yl + dy0) * 68 + xc + dx0) * 4];
        A.u[1] = *(const uint2*)&img[((yl + dy1) * 68 + xc + dx1) * 4];
        acc[rb][t] = __builtin_amdgcn_mfma_f32_16x16x32_f16(A.h, Bf0, acc[rb][t], 0, 0, 0);
        union { half8 h; uint2 u[2]; } A1;
        A1.u[0] = *(const uint2*)&img[(q == 0) ? ((yl + 1) * 68 + xc + 1) * 4 : zoff];
        A1.u[1] = make_uint2(0u, 0u);
        acc[rb][t] = __builtin_amdgcn_mfma_f32_16x16x32_f16(A1.h, Bf1, acc[rb][t], 0, 0, 0);
      }
    }
    if (ln < 12) {
#pragma unroll
      for (int t = 0; t < 4; ++t) {
        const floatx4 ca = acc[0][t], cb = acc[1][t];
        float v0 = fmaxf(fmaxf(ca.x, ca.y), fmaxf(cb.x, cb.y)) + bv;
        float v1 = fmaxf(fmaxf(ca.z, ca.w), fmaxf(cb.z, cb.w)) + bv;
        v0 = (v0 > 0.f) ? v0 : 0.001f * v0;
        v1 = (v1 > 0.f) ? v1 : 0.001f * v1;
        const int px = t * 8 + q * 2;
        ptile[(pr * 32 + px) * 12 + ln]     = __float2half(v0);
        ptile[(pr * 32 + px + 1) * 12 + ln] = __float2half(v1);
      }
    }
  }
  __syncthreads();

  // FC: thread = 4 pixels (48 contiguous halves); 12 hid dots, 2-hid blocking
  float af[48];
#pragma unroll
  for (int j = 0; j < 6; ++j) {
    const half8 a = *((const half8*)ptile + tid * 6 + j);
#pragma unroll
    for (int e = 0; e < 8; ++e) af[j * 8 + e] = (float)a[e];
  }
  float s[12];
#pragma unroll 1
  for (int hp = 0; hp < 6; ++hp) {
    const __half* w0 = Wpp + (size_t)(2 * hp) * 12288 + tid * 48;
    half8 wv0[6], wv1[6];
#pragma unroll
    for (int j = 0; j < 6; ++j) { wv0[j] = *((const half8*)w0 + j); wv1[j] = *((const half8*)(w0 + 12288) + j); }
    float s0 = 0.f, s1 = 0.f;
#pragma unroll
    for (int j = 0; j < 6; ++j)
#pragma unroll
      for (int e = 0; e < 8; ++e) {
        s0 = fmaf(af[j * 8 + e], (float)wv0[j][e], s0);
        s1 = fmaf(af[j * 8 + e], (float)wv1[j][e], s1);
      }
    s[2 * hp] = s0; s[2 * hp + 1] = s1;
  }
#pragma unroll
  for (int i = 0; i < 12; ++i)
    for (int off = 32; off > 0; off >>= 1) s[i] += __shfl_down(s[i], off, 64);
  if (lane == 0)
#pragma unroll
    for (int i = 0; i < 12; ++i) red[wave][i] = s[i];
  __syncthreads();
  if (tid < 12)
    pb[b * 12 + tid] = red[0][tid] + red[1][tid] + red[2][tid] + red[3][tid] + Plb[dm * 12 + tid];
}

// ---------------- fused shared tower: conv1+conv2+conv3+fc ------------------
// One block per image; dynamic LDS (154,496 B).
__global__ __launch_bounds__(256)
void k_tower(const float* __restrict__ xin, const __half* __restrict__ B36,
             const float* __restrict__ Winb, const __half* __restrict__ Bp,
             const float* __restrict__ b48g, const __half* __restrict__ Wshp,
             const float* __restrict__ Wfcb, float* __restrict__ hb) {
  extern __shared__ __align__(16) char ldsx[];
  __half* uA  = (__half*)ldsx;                 // img [66][68][4] / hid Bpack (33.8KB)
  __half* A1h = (__half*)(ldsx + 35904);       // conv1-out records [34][34][40h] / fcstage
  __half* O2h = (__half*)(ldsx + 128384);      // conv2-out records [18][18][40h]
  float*  red = (float*)(ldsx + 154304);       // [4][12]
  const int tid = threadIdx.x, b = blockIdx.x;
  const int lane = tid & 63, wave = tid >> 6, ln = lane & 15, q = lane >> 4;

  // ---- T1: stage image + zero all halos ----
  float c0[16], c1[16], c2[16];
#pragma unroll
  for (int u = 0; u < 16; ++u) {
    const int i = tid + u * 256;
    const int y = i >> 6, px = i & 63;
    const float* p0 = xin + (size_t)b * 12288 + y * 64 + px;
    c0[u] = p0[0]; c1[u] = p0[4096]; c2[u] = p0[8192];
  }
  half8 Bf[2][3];
#pragma unroll
  for (int s = 0; s < 2; ++s)
#pragma unroll
    for (int nt = 0; nt < 3; ++nt)
      Bf[s][nt] = *(const half8*)(B36 + ((s * 3 + nt) * 64 + lane) * 8);
  float bv36[3];
#pragma unroll
  for (int nt = 0; nt < 3; ++nt) {
    const int oc = nt * 16 + ln;
    bv36[nt] = (oc < 36) ? Winb[oc] : 0.f;
  }
  for (int i = tid; i < 264; i += 256) {       // img halo
    int hidx;
    if (i < 136) { const int r = (i < 68) ? 0 : 65; hidx = (r * 68 + (i % 68)) * 4; }
    else { const int j = i - 136; const int r = 1 + (j & 63); hidx = (r * 68 + ((j < 64) ? 0 : 65)) * 4; }
    *(unsigned long long*)&uA[hidx] = 0ULL;
  }
  for (int u = tid; u < 1320; u += 256) {      // A1 record halo (132 recs x 10 u64)
    const int rec = u / 10, part = u % 10;
    int r, c;
    if (rec < 34) { r = 0; c = rec; }
    else if (rec < 68) { r = 33; c = rec - 34; }
    else if (rec < 100) { r = rec - 68 + 1; c = 0; }
    else { r = rec - 100 + 1; c = 33; }
    *(unsigned long long*)&A1h[(r * 34 + c) * 40 + part * 4] = 0ULL;
  }
  for (int u = tid; u < 680; u += 256) {       // O2 record halo (68 recs)
    const int rec = u / 10, part = u % 10;
    int r, c;
    if (rec < 18) { r = 0; c = rec; }
    else if (rec < 36) { r = 17; c = rec - 18; }
    else if (rec < 52) { r = rec - 36 + 1; c = 0; }
    else { r = rec - 52 + 1; c = 17; }
    *(unsigned long long*)&O2h[(r * 18 + c) * 40 + part * 4] = 0ULL;
  }
#pragma unroll
  for (int u = 0; u < 16; ++u) {
    const int i = tid + u * 256;
    const int y = i >> 6, px = i & 63;
    __half2 lo = __floats2half2_rn(c0[u], c1[u]);
    __half2 hi = __floats2half2_rn(c2[u], 0.f);
    *(uint2*)&uA[((y + 1) * 68 + px + 1) * 4] =
        make_uint2(*(unsigned int*)&lo, *(unsigned int*)&hi);
  }
  __syncthreads();

  // ---- T2: conv1 + pool -> A1 records ----
  {
    const int dy0_t[4] = {-1, -1, 0, 1}, dx0_t[4] = {-1, 1, 0, -1};
    const int dy1_t[4] = {-1, 0, 0, 1},  dx1_t[4] = {0, -1, 1, 0};
    const int dy0 = dy0_t[q], dx0 = dx0_t[q], dy1 = dy1_t[q], dx1 = dx1_t[q];
    const int zoff = (65 * 68 + 66) * 4;
#pragma unroll 1
    for (int kk = 0; kk < 8; ++kk) {
      const int pr = 4 * kk + wave;
      floatx4 acc[2][4][3];
#pragma unroll
      for (int rb = 0; rb < 2; ++rb)
#pragma unroll
        for (int t = 0; t < 4; ++t)
#pragma unroll
          for (int nt = 0; nt < 3; ++nt) acc[rb][t][nt] = (floatx4){0.f, 0.f, 0.f, 0.f};
#pragma unroll
      for (int rb = 0; rb < 2; ++rb) {
        const int yl = 2 * pr + rb + 1;
#pragma unroll
        for (int t = 0; t < 4; ++t) {
          const int xc = t * 16 + ln + 1;
          union { half8 h; uint2 u[2]; } A;
          A.u[0] = *(const uint2*)&uA[((yl + dy0) * 68 + xc + dx0) * 4];
          A.u[1] = *(const uint2*)&uA[((yl + dy1) * 68 + xc + dx1) * 4];
#pragma unroll
          for (int nt = 0; nt < 3; ++nt)
            acc[rb][t][nt] = __builtin_amdgcn_mfma_f32_16x16x32_f16(A.h, Bf[0][nt], acc[rb][t][nt], 0, 0, 0);
          union { half8 h; uint2 u[2]; } A1v;
          A1v.u[0] = *(const uint2*)&uA[(q == 0) ? ((yl + 1) * 68 + xc + 1) * 4 : zoff];
          A1v.u[1] = make_uint2(0u, 0u);
#pragma unroll
          for (int nt = 0; nt < 3; ++nt)
            acc[rb][t][nt] = __builtin_amdgcn_mfma_f32_16x16x32_f16(A1v.h, Bf[1][nt], acc[rb][t][nt], 0, 0, 0);
        }
      }
#pragma unroll
      for (int t = 0; t < 4; ++t)
#pragma unroll
        for (int nt = 0; nt < 3; ++nt) {
          const int oc = nt * 16 + ln;
          if (oc < 36) {
            const floatx4 ca = acc[0][t][nt], cb = acc[1][t][nt];
            const float v0 = fmaxf(fmaxf(fmaxf(ca.x, ca.y), fmaxf(cb.x, cb.y)) + bv36[nt], 0.f);
            const float v1 = fmaxf(fmaxf(fmaxf(ca.z, ca.w), fmaxf(cb.z, cb.w)) + bv36[nt], 0.f);
            const int px = t * 8 + q * 2;
            A1h[((pr + 1) * 34 + px + 1) * 40 + oc] = __float2half(v0);
            A1h[((pr + 1) * 34 + px + 2) * 40 + oc] = __float2half(v1);
          }
        }
    }
  }
  __syncthreads();

  // ---- T3: load hid Bpack into uA (img dead) ----
  {
    uint4 bpr[9];
#pragma unroll
    for (int u = 0; u < 9; ++u) {
      const int i = tid + u * 256;
      bpr[u] = (i < 2112) ? ((const uint4*)Bp)[i] : make_uint4(0, 0, 0, 0);
    }
#pragma unroll
    for (int u = 0; u < 9; ++u) {
      const int i = tid + u * 256;
      if (i < 2112) ((uint4*)uA)[i] = bpr[u];
    }
  }
  float bb[3];
#pragma unroll
  for (int nt = 0; nt < 3; ++nt) bb[nt] = b48g[nt * 16 + ln];
  __syncthreads();

  const __half* lB = uA + lane * 8;
  const int tA = 2 * q, tB = 2 * q + 1;

  // ---- T4: conv2 + pool -> O2 records ----
  {
    const int roA = ((tA / 3) * 34 + (tA % 3)) * 40 + 32;
    const int roB = ((tB / 3) * 34 + (tB % 3)) * 40 + 32;
    const int roC = (2 * 34 + 2) * 40 + 32;
#pragma unroll 1
    for (int it = 0; it < 4; ++it) {
      const int r0 = 8 * it + 2 * wave;
      int baseA[4];
#pragma unroll
      for (int mt = 0; mt < 4; ++mt)
        baseA[mt] = ((r0 + (mt >> 1)) * 34 + (mt & 1) * 16 + ln) * 40 + q * 8;
      floatx4 acc[4][3];
#pragma unroll
      for (int mt = 0; mt < 4; ++mt)
#pragma unroll
        for (int nt = 0; nt < 3; ++nt) acc[mt][nt] = (floatx4){0.f, 0.f, 0.f, 0.f};
#pragma unroll
      for (int s = 0; s < 9; ++s) {
        const int ky = s / 3, kx = s % 3;
        const half8 B0 = *(const half8*)&lB[(s * 3 + 0) * 512];
        const half8 B1 = *(const half8*)&lB[(s * 3 + 1) * 512];
        const half8 B2 = *(const half8*)&lB[(s * 3 + 2) * 512];
#pragma unroll
        for (int mt = 0; mt < 4; ++mt) {
          const half8 A = *(const half8*)&A1h[baseA[mt] + (ky * 34 + kx) * 40];
          acc[mt][0] = __builtin_amdgcn_mfma_f32_16x16x32_f16(A, B0, acc[mt][0], 0, 0, 0);
          acc[mt][1] = __builtin_amdgcn_mfma_f32_16x16x32_f16(A, B1, acc[mt][1], 0, 0, 0);
          acc[mt][2] = __builtin_amdgcn_mfma_f32_16x16x32_f16(A, B2, acc[mt][2], 0, 0, 0);
        }
      }
#pragma unroll
      for (int s = 9; s <= 10; ++s) {
        const half8 B0 = *(const half8*)&lB[(s * 3 + 0) * 512];
        const half8 B1 = *(const half8*)&lB[(s * 3 + 1) * 512];
        const half8 B2 = *(const half8*)&lB[(s * 3 + 2) * 512];
        const int oA = (s == 9) ? roA : roC, oB = (s == 9) ? roB : roC;
#pragma unroll
        for (int mt = 0; mt < 4; ++mt) {
          union { half8 h; uint2 u[2]; } au;
          au.u[0] = *(const uint2*)&A1h[baseA[mt] + oA];
          au.u[1] = *(const uint2*)&A1h[baseA[mt] + oB];
          acc[mt][0] = __builtin_amdgcn_mfma_f32_16x16x32_f16(au.h, B0, acc[mt][0], 0, 0, 0);
          acc[mt][1] = __builtin_amdgcn_mfma_f32_16x16x32_f16(au.h, B1, acc[mt][1], 0, 0, 0);
          acc[mt][2] = __builtin_amdgcn_mfma_f32_16x16x32_f16(au.h, B2, acc[mt][2], 0, 0, 0);
        }
      }
      const int py = 4 * it + wave;
#pragma unroll
      for (int h = 0; h < 2; ++h)
#pragma unroll
        for (int nt = 0; nt < 3; ++nt) {
          const int oc = nt * 16 + ln;
          if (oc < 36) {
            const floatx4 ca = acc[h][nt], cb = acc[2 + h][nt];
            const float v0 = fmaxf(fmaxf(fmaxf(ca.x, ca.y), fmaxf(cb.x, cb.y)) + bb[nt], 0.f);
            const float v1 = fmaxf(fmaxf(fmaxf(ca.z, ca.w), fmaxf(cb.z, cb.w)) + bb[nt], 0.f);
            const int px = h * 8 + q * 2;
            O2h[((py + 1) * 18 + px + 1) * 40 + oc] = __float2half(v0);
            O2h[((py + 1) * 18 + px + 2) * 40 + oc] = __float2half(v1);
          }
        }
    }
  }
  __syncthreads();

  // ---- T5: conv3 + pool -> fcstage (aliases A1 base, [64px][36]) ----
  {
    const int roA = ((tA / 3) * 18 + (tA % 3)) * 40 + 32;
    const int roB = ((tB / 3) * 18 + (tB % 3)) * 40 + 32;
    const int roC = (2 * 18 + 2) * 40 + 32;
    int baseA[4];
#pragma unroll
    for (int mt = 0; mt < 4; ++mt)
      baseA[mt] = ((4 * wave + mt) * 18 + ln) * 40 + q * 8;
    floatx4 acc[4][3];
#pragma unroll
    for (int mt = 0; mt < 4; ++mt)
#pragma unroll
      for (int nt = 0; nt < 3; ++nt) acc[mt][nt] = (floatx4){0.f, 0.f, 0.f, 0.f};
#pragma unroll
    for (int s = 0; s < 9; ++s) {
      const int ky = s / 3, kx = s % 3;
      const half8 B0 = *(const half8*)&lB[(s * 3 + 0) * 512];
      const half8 B1 = *(const half8*)&lB[(s * 3 + 1) * 512];
      const half8 B2 = *(const half8*)&lB[(s * 3 + 2) * 512];
#pragma unroll
      for (int mt = 0; mt < 4; ++mt) {
        const half8 A = *(const half8*)&O2h[baseA[mt] + (ky * 18 + kx) * 40];
        acc[mt][0] = __builtin_amdgcn_mfma_f32_16x16x32_f16(A, B0, acc[mt][0], 0, 0, 0);
        acc[mt][1] = __builtin_amdgcn_mfma_f32_16x16x32_f16(A, B1, acc[mt][1], 0, 0, 0);
        acc[mt][2] = __builtin_amdgcn_mfma_f32_16x16x32_f16(A, B2, acc[mt][2], 0, 0, 0);
      }
    }
#pragma unroll
    for (int s = 9; s <= 10; ++s) {
      const half8 B0 = *(const half8*)&lB[(s * 3 + 0) * 512];
      const half8 B1 = *(const half8*)&lB[(s * 3 + 1) * 512];
      const half8 B2 = *(const half8*)&lB[(s * 3 + 2) * 512];
      const int oA = (s == 9) ? roA : roC, oB = (s == 9) ? roB : roC;
#pragma unroll
      for (int mt = 0; mt < 4; ++mt) {
        union { half8 h; uint2 u[2]; } au;
        au.u[0] = *(const uint2*)&O2h[baseA[mt] + oA];
        au.u[1] = *(const uint2*)&O2h[baseA[mt] + oB];
        acc[mt][0] = __builtin_amdgcn_mfma_f32_16x16x32_f16(au.h, B0, acc[mt][0], 0, 0, 0);
        acc[mt][1] = __builtin_amdgcn_mfma_f32_16x16x32_f16(au.h, B1, acc[mt][1], 0, 0, 0);
        acc[mt][2] = __builtin_amdgcn_mfma_f32_16x16x32_f16(au.h, B2, acc[mt][2], 0, 0, 0);
      }
    }
#pragma unroll
    for (int pp = 0; pp < 2; ++pp) {
      const int py = 2 * wave + pp;
#pragma unroll
      for (int nt = 0; nt < 3; ++nt) {
        const int oc = nt * 16 + ln;
        if (oc < 36) {
          const floatx4 ca = acc[2 * pp][nt], cb = acc[2 * pp + 1][nt];
          const float v0 = fmaxf(fmaxf(fmaxf(ca.x, ca.y), fmaxf(cb.x, cb.y)) + bb[nt], 0.f);
          const float v1 = fmaxf(fmaxf(fmaxf(ca.z, ca.w), fmaxf(cb.z, cb.w)) + bb[nt], 0.f);
          const int px = q * 2;
          A1h[(py * 8 + px) * 36 + oc]     = __float2half(v0);
          A1h[(py * 8 + px + 1) * 36 + oc] = __float2half(v1);
        }
      }
    }
  }
  __syncthreads();

  // ---- T6: shared FC [2304]->[12] + relu ----
  {
    const int px_lin = tid >> 2, part = tid & 3;
    const int k0 = px_lin * 36 + part * 9;
    float af[9];
#pragma unroll
    for (int j = 0; j < 9; ++j) af[j] = __half2float(A1h[k0 + j]);
    float s[12];
#pragma unroll
    for (int hid = 0; hid < 12; ++hid) {
      const __half* w = Wshp + hid * 2304 + k0;
      float acc = 0.f;
#pragma unroll
      for (int j = 0; j < 9; ++j) acc = fmaf(af[j], __half2float(w[j]), acc);
      s[hid] = acc;
    }
#pragma unroll
    for (int i = 0; i < 12; ++i)
      for (int off = 32; off > 0; off >>= 1) s[i] += __shfl_down(s[i], off, 64);
    if (lane == 0)
#pragma unroll
      for (int i = 0; i < 12; ++i) red[wave * 12 + i] = s[i];
    __syncthreads();
    if (tid < 12)
      hb[b * 12 + tid] = fmaxf(red[tid] + red[12 + tid] + red[24 + tid] + red[36 + tid] + Wfcb[tid], 0.f);
  }
}

// ---------------- per-sample MoE heads --------------------------------------
__global__ __launch_bounds__(256)
void k_heads(const float* __restrict__ h, const float* __restrict__ p,
             const int* __restrict__ tt,
             const float* __restrict__ W1, const float* __restrict__ b1,
             const float* __restrict__ W2, const float* __restrict__ b2,
             const float* __restrict__ W3, const float* __restrict__ b3,
             float* __restrict__ out) {
  const int b = blockIdx.x * 256 + threadIdx.x;
  if (b >= 1024) return;
  const int t = tt[b];
  float xv[24];
#pragma unroll
  for (int i = 0; i < 12; ++i) xv[i] = h[b * 12 + i];
#pragma unroll
  for (int i = 0; i < 12; ++i) xv[12 + i] = p[b * 12 + i];
  float h1[28];
  const float* w1 = W1 + t * 28 * 24;
#pragma unroll 1
  for (int i = 0; i < 28; ++i) {
    float s = b1[t * 28 + i];
#pragma unroll
    for (int j = 0; j < 24; ++j) s = fmaf(w1[i * 24 + j], xv[j], s);
    h1[i] = fmaxf(s, 0.f);
  }
  float h2[14];
  const float* w2 = W2 + t * 14 * 28;
#pragma unroll 1
  for (int i = 0; i < 14; ++i) {
    float s = b2[t * 14 + i];
#pragma unroll
    for (int j = 0; j < 28; ++j) s = fmaf(w2[i * 28 + j], h1[j], s);
    h2[i] = fmaxf(s, 0.f);
  }
  const float* w3 = W3 + t * 5 * 14;
#pragma unroll
  for (int i = 0; i < 5; ++i) {
    float s = b3[t * 5 + i];
#pragma unroll
    for (int j = 0; j < 14; ++j) s = fmaf(w3[i * 14 + j], h2[j], s);
    out[b * 5 + i] = s;
  }
}

extern "C" void kernel_launch(void* const* d_in, const int* in_sizes, int n_in,
                              void* d_out, int out_size, void* d_ws, size_t ws_size,
                              hipStream_t stream) {
  const float* x_s  = (const float*)d_in[0];
  const float* x_p  = (const float*)d_in[1];
  const int*   tt   = (const int*)d_in[2];
  const int*   dom  = (const int*)d_in[3];
  const float* WinW = (const float*)d_in[4];
  const float* Winb = (const float*)d_in[5];
  const float* WhW  = (const float*)d_in[6];
  const float* Whb  = (const float*)d_in[7];
  const float* WfcW = (const float*)d_in[8];
  const float* Wfcb = (const float*)d_in[9];
  const float* PcW  = (const float*)d_in[10];
  const float* Pcb  = (const float*)d_in[11];
  const float* PlW  = (const float*)d_in[12];
  const float* Plb  = (const float*)d_in[13];
  const float* H1W  = (const float*)d_in[14];
  const float* H1b  = (const float*)d_in[15];
  const float* H2W  = (const float*)d_in[16];
  const float* H2b  = (const float*)d_in[17];
  const float* H3W  = (const float*)d_in[18];
  const float* H3b  = (const float*)d_in[19];
  float* out = (float*)d_out;

  char* ws = (char*)d_ws;
  __half* Bp   = (__half*)(ws + 0);        // 33,792 B
  float*  b48  = (float*)(ws + 33792);     // 192
  __half* B36  = (__half*)(ws + 33984);    // 6,144
  __half* B12  = (__half*)(ws + 40128);    // 2,048
  __half* Wpp  = (__half*)(ws + 42176);    // [12][12288] f16 = 294,912
  __half* Wshp = (__half*)(ws + 337088);   // [12][2304]  f16 = 55,296
  float*  hb   = (float*)(ws + 392384);    // [1024][12]
  float*  pb   = (float*)(ws + 441536);    // [1024][12]

  k_prepack_small<<<1, 256, 0, stream>>>(WhW, Whb, WinW, PcW, dom, Bp, b48, B36, B12);
  k_prepack_fcp<<<96, 256, 0, stream>>>(PlW, dom, WfcW, Wpp, Wshp);
  k_priv<<<1024, 256, 0, stream>>>(x_p, B12, Pcb, dom, Wpp, Plb, pb);
  k_tower<<<1024, 256, 154496, stream>>>(x_s, B36, Winb, Bp, b48, Wshp, Wfcb, hb);
  k_heads<<<4, 256, 0, stream>>>(hb, pb, tt, H1W, H1b, H2W, H2b, H3W, H3b, out);
}

// Round 7
// 299.657 us; speedup vs baseline: 3.6610x; 1.0743x over previous
//
#include <hip/hip_runtime.h>
#include <hip/hip_fp16.h>

typedef _Float16 half8 __attribute__((ext_vector_type(8)));
typedef float floatx4 __attribute__((ext_vector_type(4)));

// ---------------- prepack: hid Bfrag + bias48 + conv_in Bfrags --------------
__global__ void k_prepack_small(const float* __restrict__ WhW, const float* __restrict__ Whb,
                                const float* __restrict__ WinW, const float* __restrict__ PcW,
                                const int* __restrict__ dom,
                                __half* __restrict__ Bpack, float* __restrict__ bias48,
                                __half* __restrict__ B36, __half* __restrict__ B12) {
  const int tid = threadIdx.x;
  const int dm = dom[0];
  for (int i = tid; i < 11 * 3 * 64 * 8; i += 256) {
    const int j = i & 7, lane = (i >> 3) & 63, nt = (i >> 9) % 3, s = i / 1536;
    const int n = lane & 15, q = lane >> 4;
    const int k = q * 8 + j;
    const int oc = nt * 16 + n;
    int tap, ch; bool valid = true;
    if (s < 9)       { tap = s;      ch = k; }
    else if (s == 9) { tap = k >> 2; ch = 32 + (k & 3); }
    else             { tap = 8;      ch = 32 + k; valid = (k < 4); }
    float v = 0.f;
    if (valid && oc < 36 && ch < 36) v = WhW[(oc * 36 + ch) * 9 + tap];
    Bpack[i] = __float2half(v);
  }
  if (tid < 48) bias48[tid] = (tid < 36) ? Whb[tid] : 0.f;
  for (int i = tid; i < 3072 + 1024; i += 256) {
    const bool is36 = i < 3072;
    const int ii = is36 ? i : i - 3072;
    const int NT = is36 ? 3 : 1, OCv = is36 ? 36 : 12;
    const int j = ii & 7, lane = (ii >> 3) & 63;
    const int nt = (ii >> 9) % NT, s = ii / (NT * 512);
    const int n = lane & 15, q = lane >> 4, oc = nt * 16 + n;
    int ky, kx, c; bool valid = (oc < OCv);
    if (s == 0) { const int pi = q * 2 + (j >> 2); ky = pi / 3; kx = pi % 3; c = j & 3; }
    else        { ky = 2; kx = 2; c = j; valid = valid && (q == 0 && j < 4); }
    valid = valid && (c < 3);
    float v = 0.f;
    if (valid) {
      const float* W = is36 ? WinW : (PcW + (size_t)dm * 12 * 27);
      v = W[((oc * 3 + c) * 3 + ky) * 3 + kx];
    }
    (is36 ? B36 : B12)[ii] = __float2half(v);
  }
}

// ---------------- prepack: plain f16 FC weights in activation-storage order -
__global__ void k_prepack_fcp(const float* __restrict__ PlW, const int* __restrict__ dom,
                              const float* __restrict__ WfcW,
                              __half* __restrict__ Wpp, __half* __restrict__ Wshp) {
  const int dm = dom[0];
  const int gid = blockIdx.x * 256 + threadIdx.x;
  const int stride = gridDim.x * 256;
  for (int i = gid; i < 147456; i += stride) {
    const int hid = i / 12288, k = i - hid * 12288;
    const int oc = k % 12, pix = k / 12;
    Wpp[i] = __float2half(PlW[((size_t)dm * 12 + hid) * 12288 + oc * 1024 + pix]);
  }
  for (int i = gid; i < 27648; i += stride) {
    const int hid = i / 2304, k = i - hid * 2304;
    const int oc = k % 36, p = k / 36;
    Wshp[i] = __float2half(WfcW[hid * 2304 + oc * 64 + p]);
  }
}

// ---------------- fused private branch: conv(3->12,leaky)+pool + FC ---------
__global__ __launch_bounds__(256)
void k_priv(const float* __restrict__ xin, const __half* __restrict__ B12,
            const float* __restrict__ Pcb, const int* __restrict__ dom,
            const __half* __restrict__ Wpp, const float* __restrict__ Plb,
            float* __restrict__ pb) {
  __shared__ __align__(16) __half img[66 * 68 * 4];
  __shared__ __align__(16) __half ptile[1024 * 12];
  __shared__ float red[4][12];
  const int tid = threadIdx.x, b = blockIdx.x;
  const int lane = tid & 63, wave = tid >> 6, ln = lane & 15, q = lane >> 4;
  const int dm = dom[0];

  float c0[16], c1[16], c2[16];
#pragma unroll
  for (int u = 0; u < 16; ++u) {
    const int i = tid + u * 256;
    const int y = i >> 6, px = i & 63;
    const float* p0 = xin + (size_t)b * 12288 + y * 64 + px;
    c0[u] = p0[0]; c1[u] = p0[4096]; c2[u] = p0[8192];
  }
  const half8 Bf0 = *(const half8*)(B12 + lane * 8);
  const half8 Bf1 = *(const half8*)(B12 + (64 + lane) * 8);
  const float bv = (ln < 12) ? Pcb[dm * 12 + ln] : 0.f;
  for (int i = tid; i < 264; i += 256) {
    int hidx;
    if (i < 136) { const int r = (i < 68) ? 0 : 65; hidx = (r * 68 + (i % 68)) * 4; }
    else { const int j = i - 136; const int r = 1 + (j & 63); hidx = (r * 68 + ((j < 64) ? 0 : 65)) * 4; }
    *(unsigned long long*)&img[hidx] = 0ULL;
  }
#pragma unroll
  for (int u = 0; u < 16; ++u) {
    const int i = tid + u * 256;
    const int y = i >> 6, px = i & 63;
    __half2 lo = __floats2half2_rn(c0[u], c1[u]);
    __half2 hi = __floats2half2_rn(c2[u], 0.f);
    *(uint2*)&img[((y + 1) * 68 + px + 1) * 4] =
        make_uint2(*(unsigned int*)&lo, *(unsigned int*)&hi);
  }
  __syncthreads();

  const int dy0_t[4] = {-1, -1, 0, 1}, dx0_t[4] = {-1, 1, 0, -1};
  const int dy1_t[4] = {-1, 0, 0, 1},  dx1_t[4] = {0, -1, 1, 0};
  const int dy0 = dy0_t[q], dx0 = dx0_t[q], dy1 = dy1_t[q], dx1 = dx1_t[q];
  const int zoff = (65 * 68 + 66) * 4;

#pragma unroll 1
  for (int kk = 0; kk < 8; ++kk) {
    const int pr = 4 * kk + wave;
    floatx4 acc[2][4];
#pragma unroll
    for (int rb = 0; rb < 2; ++rb)
#pragma unroll
      for (int t = 0; t < 4; ++t) acc[rb][t] = (floatx4){0.f, 0.f, 0.f, 0.f};
#pragma unroll
    for (int rb = 0; rb < 2; ++rb) {
      const int yl = 2 * pr + rb + 1;
#pragma unroll
      for (int t = 0; t < 4; ++t) {
        const int xc = t * 16 + ln + 1;
        union { half8 h; uint2 u[2]; } A;
        A.u[0] = *(const uint2*)&img[((yl + dy0) * 68 + xc + dx0) * 4];
        A.u[1] = *(const uint2*)&img[((yl + dy1) * 68 + xc + dx1) * 4];
        acc[rb][t] = __builtin_amdgcn_mfma_f32_16x16x32_f16(A.h, Bf0, acc[rb][t], 0, 0, 0);
        union { half8 h; uint2 u[2]; } A1;
        A1.u[0] = *(const uint2*)&img[(q == 0) ? ((yl + 1) * 68 + xc + 1) * 4 : zoff];
        A1.u[1] = make_uint2(0u, 0u);
        acc[rb][t] = __builtin_amdgcn_mfma_f32_16x16x32_f16(A1.h, Bf1, acc[rb][t], 0, 0, 0);
      }
    }
    if (ln < 12) {
#pragma unroll
      for (int t = 0; t < 4; ++t) {
        const floatx4 ca = acc[0][t], cb = acc[1][t];
        float v0 = fmaxf(fmaxf(ca.x, ca.y), fmaxf(cb.x, cb.y)) + bv;
        float v1 = fmaxf(fmaxf(ca.z, ca.w), fmaxf(cb.z, cb.w)) + bv;
        v0 = (v0 > 0.f) ? v0 : 0.001f * v0;
        v1 = (v1 > 0.f) ? v1 : 0.001f * v1;
        const int px = t * 8 + q * 2;
        ptile[(pr * 32 + px) * 12 + ln]     = __float2half(v0);
        ptile[(pr * 32 + px + 1) * 12 + ln] = __float2half(v1);
      }
    }
  }
  __syncthreads();

  float af[48];
#pragma unroll
  for (int j = 0; j < 6; ++j) {
    const half8 a = *((const half8*)ptile + tid * 6 + j);
#pragma unroll
    for (int e = 0; e < 8; ++e) af[j * 8 + e] = (float)a[e];
  }
  float s[12];
#pragma unroll 1
  for (int hp = 0; hp < 6; ++hp) {
    const __half* w0 = Wpp + (size_t)(2 * hp) * 12288 + tid * 48;
    half8 wv0[6], wv1[6];
#pragma unroll
    for (int j = 0; j < 6; ++j) { wv0[j] = *((const half8*)w0 + j); wv1[j] = *((const half8*)(w0 + 12288) + j); }
    float s0 = 0.f, s1 = 0.f;
#pragma unroll
    for (int j = 0; j < 6; ++j)
#pragma unroll
      for (int e = 0; e < 8; ++e) {
        s0 = fmaf(af[j * 8 + e], (float)wv0[j][e], s0);
        s1 = fmaf(af[j * 8 + e], (float)wv1[j][e], s1);
      }
    s[2 * hp] = s0; s[2 * hp + 1] = s1;
  }
#pragma unroll
  for (int i = 0; i < 12; ++i)
    for (int off = 32; off > 0; off >>= 1) s[i] += __shfl_down(s[i], off, 64);
  if (lane == 0)
#pragma unroll
    for (int i = 0; i < 12; ++i) red[wave][i] = s[i];
  __syncthreads();
  if (tid < 12)
    pb[b * 12 + tid] = red[0][tid] + red[1][tid] + red[2][tid] + red[3][tid] + Plb[dm * 12 + tid];
}

// ---------------- fused shared tower: conv1+conv2+conv3+fc, 512 threads -----
// 8 waves = 2 waves/SIMD to hide LDS/MFMA latency at 1 block/CU.
__global__ __launch_bounds__(512)
void k_tower(const float* __restrict__ xin, const __half* __restrict__ B36,
             const float* __restrict__ Winb, const __half* __restrict__ Bp,
             const float* __restrict__ b48g, const __half* __restrict__ Wshp,
             const float* __restrict__ Wfcb, float* __restrict__ hb) {
  extern __shared__ __align__(16) char ldsx[];
  __half* uA  = (__half*)ldsx;                 // img [66][68][4] / hid Bpack
  __half* A1h = (__half*)(ldsx + 35904);       // conv1-out records [34][34][40h] / fcstage
  __half* O2h = (__half*)(ldsx + 128384);      // conv2-out records [18][18][40h]
  float*  red = (float*)(ldsx + 154304);       // [4][12]
  const int tid = threadIdx.x, b = blockIdx.x;
  const int lane = tid & 63, wave = tid >> 6, ln = lane & 15, q = lane >> 4;

  // ---- T1: stage image + zero all halos ----
  float c0[8], c1[8], c2[8];
#pragma unroll
  for (int u = 0; u < 8; ++u) {
    const int i = tid + u * 512;
    const int y = i >> 6, px = i & 63;
    const float* p0 = xin + (size_t)b * 12288 + y * 64 + px;
    c0[u] = p0[0]; c1[u] = p0[4096]; c2[u] = p0[8192];
  }
  half8 Bf[2][3];
#pragma unroll
  for (int s = 0; s < 2; ++s)
#pragma unroll
    for (int nt = 0; nt < 3; ++nt)
      Bf[s][nt] = *(const half8*)(B36 + ((s * 3 + nt) * 64 + lane) * 8);
  float bv36[3];
#pragma unroll
  for (int nt = 0; nt < 3; ++nt) {
    const int oc = nt * 16 + ln;
    bv36[nt] = (oc < 36) ? Winb[oc] : 0.f;
  }
  for (int i = tid; i < 264; i += 512) {
    int hidx;
    if (i < 136) { const int r = (i < 68) ? 0 : 65; hidx = (r * 68 + (i % 68)) * 4; }
    else { const int j = i - 136; const int r = 1 + (j & 63); hidx = (r * 68 + ((j < 64) ? 0 : 65)) * 4; }
    *(unsigned long long*)&uA[hidx] = 0ULL;
  }
  for (int u = tid; u < 1320; u += 512) {
    const int rec = u / 10, part = u % 10;
    int r, c;
    if (rec < 34) { r = 0; c = rec; }
    else if (rec < 68) { r = 33; c = rec - 34; }
    else if (rec < 100) { r = rec - 68 + 1; c = 0; }
    else { r = rec - 100 + 1; c = 33; }
    *(unsigned long long*)&A1h[(r * 34 + c) * 40 + part * 4] = 0ULL;
  }
  for (int u = tid; u < 680; u += 512) {
    const int rec = u / 10, part = u % 10;
    int r, c;
    if (rec < 18) { r = 0; c = rec; }
    else if (rec < 36) { r = 17; c = rec - 18; }
    else if (rec < 52) { r = rec - 36 + 1; c = 0; }
    else { r = rec - 52 + 1; c = 17; }
    *(unsigned long long*)&O2h[(r * 18 + c) * 40 + part * 4] = 0ULL;
  }
#pragma unroll
  for (int u = 0; u < 8; ++u) {
    const int i = tid + u * 512;
    const int y = i >> 6, px = i & 63;
    __half2 lo = __floats2half2_rn(c0[u], c1[u]);
    __half2 hi = __floats2half2_rn(c2[u], 0.f);
    *(uint2*)&uA[((y + 1) * 68 + px + 1) * 4] =
        make_uint2(*(unsigned int*)&lo, *(unsigned int*)&hi);
  }
  __syncthreads();

  // ---- T2: conv1 + pool -> A1 records (8 waves x 4 pooled rows) ----
  {
    const int dy0_t[4] = {-1, -1, 0, 1}, dx0_t[4] = {-1, 1, 0, -1};
    const int dy1_t[4] = {-1, 0, 0, 1},  dx1_t[4] = {0, -1, 1, 0};
    const int dy0 = dy0_t[q], dx0 = dx0_t[q], dy1 = dy1_t[q], dx1 = dx1_t[q];
    const int zoff = (65 * 68 + 66) * 4;
#pragma unroll 1
    for (int kk = 0; kk < 4; ++kk) {
      const int pr = 8 * kk + wave;
      floatx4 acc[2][4][3];
#pragma unroll
      for (int rb = 0; rb < 2; ++rb)
#pragma unroll
        for (int t = 0; t < 4; ++t)
#pragma unroll
          for (int nt = 0; nt < 3; ++nt) acc[rb][t][nt] = (floatx4){0.f, 0.f, 0.f, 0.f};
#pragma unroll
      for (int rb = 0; rb < 2; ++rb) {
        const int yl = 2 * pr + rb + 1;
#pragma unroll
        for (int t = 0; t < 4; ++t) {
          const int xc = t * 16 + ln + 1;
          union { half8 h; uint2 u[2]; } A;
          A.u[0] = *(const uint2*)&uA[((yl + dy0) * 68 + xc + dx0) * 4];
          A.u[1] = *(const uint2*)&uA[((yl + dy1) * 68 + xc + dx1) * 4];
#pragma unroll
          for (int nt = 0; nt < 3; ++nt)
            acc[rb][t][nt] = __builtin_amdgcn_mfma_f32_16x16x32_f16(A.h, Bf[0][nt], acc[rb][t][nt], 0, 0, 0);
          union { half8 h; uint2 u[2]; } A1v;
          A1v.u[0] = *(const uint2*)&uA[(q == 0) ? ((yl + 1) * 68 + xc + 1) * 4 : zoff];
          A1v.u[1] = make_uint2(0u, 0u);
#pragma unroll
          for (int nt = 0; nt < 3; ++nt)
            acc[rb][t][nt] = __builtin_amdgcn_mfma_f32_16x16x32_f16(A1v.h, Bf[1][nt], acc[rb][t][nt], 0, 0, 0);
        }
      }
#pragma unroll
      for (int t = 0; t < 4; ++t)
#pragma unroll
        for (int nt = 0; nt < 3; ++nt) {
          const int oc = nt * 16 + ln;
          if (oc < 36) {
            const floatx4 ca = acc[0][t][nt], cb = acc[1][t][nt];
            const float v0 = fmaxf(fmaxf(fmaxf(ca.x, ca.y), fmaxf(cb.x, cb.y)) + bv36[nt], 0.f);
            const float v1 = fmaxf(fmaxf(fmaxf(ca.z, ca.w), fmaxf(cb.z, cb.w)) + bv36[nt], 0.f);
            const int px = t * 8 + q * 2;
            A1h[((pr + 1) * 34 + px + 1) * 40 + oc] = __float2half(v0);
            A1h[((pr + 1) * 34 + px + 2) * 40 + oc] = __float2half(v1);
          }
        }
    }
  }
  __syncthreads();

  // ---- T3: load hid Bpack into uA (img dead) ----
  {
    uint4 bpr[5];
#pragma unroll
    for (int u = 0; u < 5; ++u) {
      const int i = tid + u * 512;
      bpr[u] = (i < 2112) ? ((const uint4*)Bp)[i] : make_uint4(0, 0, 0, 0);
    }
#pragma unroll
    for (int u = 0; u < 5; ++u) {
      const int i = tid + u * 512;
      if (i < 2112) ((uint4*)uA)[i] = bpr[u];
    }
  }
  float bb[3];
#pragma unroll
  for (int nt = 0; nt < 3; ++nt) bb[nt] = b48g[nt * 16 + ln];
  __syncthreads();

  const __half* lB = uA + lane * 8;
  const int tA = 2 * q, tB = 2 * q + 1;

  // ---- T4: conv2 + pool -> O2 records (8 waves x 2 pooled rows) ----
  {
    const int roA = ((tA / 3) * 34 + (tA % 3)) * 40 + 32;
    const int roB = ((tB / 3) * 34 + (tB % 3)) * 40 + 32;
    const int roC = (2 * 34 + 2) * 40 + 32;
#pragma unroll 1
    for (int it = 0; it < 2; ++it) {
      const int r0 = 16 * it + 2 * wave;
      int baseA[4];
#pragma unroll
      for (int mt = 0; mt < 4; ++mt)
        baseA[mt] = ((r0 + (mt >> 1)) * 34 + (mt & 1) * 16 + ln) * 40 + q * 8;
      floatx4 acc[4][3];
#pragma unroll
      for (int mt = 0; mt < 4; ++mt)
#pragma unroll
        for (int nt = 0; nt < 3; ++nt) acc[mt][nt] = (floatx4){0.f, 0.f, 0.f, 0.f};
#pragma unroll
      for (int s = 0; s < 9; ++s) {
        const int ky = s / 3, kx = s % 3;
        const half8 B0 = *(const half8*)&lB[(s * 3 + 0) * 512];
        const half8 B1 = *(const half8*)&lB[(s * 3 + 1) * 512];
        const half8 B2 = *(const half8*)&lB[(s * 3 + 2) * 512];
#pragma unroll
        for (int mt = 0; mt < 4; ++mt) {
          const half8 A = *(const half8*)&A1h[baseA[mt] + (ky * 34 + kx) * 40];
          acc[mt][0] = __builtin_amdgcn_mfma_f32_16x16x32_f16(A, B0, acc[mt][0], 0, 0, 0);
          acc[mt][1] = __builtin_amdgcn_mfma_f32_16x16x32_f16(A, B1, acc[mt][1], 0, 0, 0);
          acc[mt][2] = __builtin_amdgcn_mfma_f32_16x16x32_f16(A, B2, acc[mt][2], 0, 0, 0);
        }
      }
#pragma unroll
      for (int s = 9; s <= 10; ++s) {
        const half8 B0 = *(const half8*)&lB[(s * 3 + 0) * 512];
        const half8 B1 = *(const half8*)&lB[(s * 3 + 1) * 512];
        const half8 B2 = *(const half8*)&lB[(s * 3 + 2) * 512];
        const int oA = (s == 9) ? roA : roC, oB = (s == 9) ? roB : roC;
#pragma unroll
        for (int mt = 0; mt < 4; ++mt) {
          union { half8 h; uint2 u[2]; } au;
          au.u[0] = *(const uint2*)&A1h[baseA[mt] + oA];
          au.u[1] = *(const uint2*)&A1h[baseA[mt] + oB];
          acc[mt][0] = __builtin_amdgcn_mfma_f32_16x16x32_f16(au.h, B0, acc[mt][0], 0, 0, 0);
          acc[mt][1] = __builtin_amdgcn_mfma_f32_16x16x32_f16(au.h, B1, acc[mt][1], 0, 0, 0);
          acc[mt][2] = __builtin_amdgcn_mfma_f32_16x16x32_f16(au.h, B2, acc[mt][2], 0, 0, 0);
        }
      }
      const int py = 8 * it + wave;
#pragma unroll
      for (int h = 0; h < 2; ++h)
#pragma unroll
        for (int nt = 0; nt < 3; ++nt) {
          const int oc = nt * 16 + ln;
          if (oc < 36) {
            const floatx4 ca = acc[h][nt], cb = acc[2 + h][nt];
            const float v0 = fmaxf(fmaxf(fmaxf(ca.x, ca.y), fmaxf(cb.x, cb.y)) + bb[nt], 0.f);
            const float v1 = fmaxf(fmaxf(fmaxf(ca.z, ca.w), fmaxf(cb.z, cb.w)) + bb[nt], 0.f);
            const int px = h * 8 + q * 2;
            O2h[((py + 1) * 18 + px + 1) * 40 + oc] = __float2half(v0);
            O2h[((py + 1) * 18 + px + 2) * 40 + oc] = __float2half(v1);
          }
        }
    }
  }
  __syncthreads();

  // ---- T5: conv3 + pool -> fcstage (8 waves x 1 pooled row) ----
  {
    const int roA = ((tA / 3) * 18 + (tA % 3)) * 40 + 32;
    const int roB = ((tB / 3) * 18 + (tB % 3)) * 40 + 32;
    const int roC = (2 * 18 + 2) * 40 + 32;
    int baseA[2];
#pragma unroll
    for (int mt = 0; mt < 2; ++mt)
      baseA[mt] = ((2 * wave + mt) * 18 + ln) * 40 + q * 8;
    floatx4 acc[2][3];
#pragma unroll
    for (int mt = 0; mt < 2; ++mt)
#pragma unroll
      for (int nt = 0; nt < 3; ++nt) acc[mt][nt] = (floatx4){0.f, 0.f, 0.f, 0.f};
#pragma unroll
    for (int s = 0; s < 9; ++s) {
      const int ky = s / 3, kx = s % 3;
      const half8 B0 = *(const half8*)&lB[(s * 3 + 0) * 512];
      const half8 B1 = *(const half8*)&lB[(s * 3 + 1) * 512];
      const half8 B2 = *(const half8*)&lB[(s * 3 + 2) * 512];
#pragma unroll
      for (int mt = 0; mt < 2; ++mt) {
        const half8 A = *(const half8*)&O2h[baseA[mt] + (ky * 18 + kx) * 40];
        acc[mt][0] = __builtin_amdgcn_mfma_f32_16x16x32_f16(A, B0, acc[mt][0], 0, 0, 0);
        acc[mt][1] = __builtin_amdgcn_mfma_f32_16x16x32_f16(A, B1, acc[mt][1], 0, 0, 0);
        acc[mt][2] = __builtin_amdgcn_mfma_f32_16x16x32_f16(A, B2, acc[mt][2], 0, 0, 0);
      }
    }
#pragma unroll
    for (int s = 9; s <= 10; ++s) {
      const half8 B0 = *(const half8*)&lB[(s * 3 + 0) * 512];
      const half8 B1 = *(const half8*)&lB[(s * 3 + 1) * 512];
      const half8 B2 = *(const half8*)&lB[(s * 3 + 2) * 512];
      const int oA = (s == 9) ? roA : roC, oB = (s == 9) ? roB : roC;
#pragma unroll
      for (int mt = 0; mt < 2; ++mt) {
        union { half8 h; uint2 u[2]; } au;
        au.u[0] = *(const uint2*)&O2h[baseA[mt] + oA];
        au.u[1] = *(const uint2*)&O2h[baseA[mt] + oB];
        acc[mt][0] = __builtin_amdgcn_mfma_f32_16x16x32_f16(au.h, B0, acc[mt][0], 0, 0, 0);
        acc[mt][1] = __builtin_amdgcn_mfma_f32_16x16x32_f16(au.h, B1, acc[mt][1], 0, 0, 0);
        acc[mt][2] = __builtin_amdgcn_mfma_f32_16x16x32_f16(au.h, B2, acc[mt][2], 0, 0, 0);
      }
    }
#pragma unroll
    for (int nt = 0; nt < 3; ++nt) {
      const int oc = nt * 16 + ln;
      if (oc < 36) {
        const floatx4 ca = acc[0][nt], cb = acc[1][nt];
        const float v0 = fmaxf(fmaxf(fmaxf(ca.x, ca.y), fmaxf(cb.x, cb.y)) + bb[nt], 0.f);
        const float v1 = fmaxf(fmaxf(fmaxf(ca.z, ca.w), fmaxf(cb.z, cb.w)) + bb[nt], 0.f);
        const int px = q * 2;
        A1h[(wave * 8 + px) * 36 + oc]     = __float2half(v0);
        A1h[(wave * 8 + px + 1) * 36 + oc] = __float2half(v1);
      }
    }
  }
  __syncthreads();

  // ---- T6: shared FC [2304]->[12] + relu (first 4 waves) ----
  if (tid < 256) {
    const int px_lin = tid >> 2, part = tid & 3;
    const int k0 = px_lin * 36 + part * 9;
    float af[9];
#pragma unroll
    for (int j = 0; j < 9; ++j) af[j] = __half2float(A1h[k0 + j]);
    float s[12];
#pragma unroll
    for (int hid = 0; hid < 12; ++hid) {
      const __half* w = Wshp + hid * 2304 + k0;
      float acc = 0.f;
#pragma unroll
      for (int j = 0; j < 9; ++j) acc = fmaf(af[j], __half2float(w[j]), acc);
      s[hid] = acc;
    }
#pragma unroll
    for (int i = 0; i < 12; ++i)
      for (int off = 32; off > 0; off >>= 1) s[i] += __shfl_down(s[i], off, 64);
    if (lane == 0)
#pragma unroll
      for (int i = 0; i < 12; ++i) red[wave * 12 + i] = s[i];
  }
  __syncthreads();
  if (tid < 12)
    hb[b * 12 + tid] = fmaxf(red[tid] + red[12 + tid] + red[24 + tid] + red[36 + tid] + Wfcb[tid], 0.f);
}

// ---------------- per-sample MoE heads --------------------------------------
__global__ __launch_bounds__(256)
void k_heads(const float* __restrict__ h, const float* __restrict__ p,
             const int* __restrict__ tt,
             const float* __restrict__ W1, const float* __restrict__ b1,
             const float* __restrict__ W2, const float* __restrict__ b2,
             const float* __restrict__ W3, const float* __restrict__ b3,
             float* __restrict__ out) {
  const int b = blockIdx.x * 256 + threadIdx.x;
  if (b >= 1024) return;
  const int t = tt[b];
  float xv[24];
#pragma unroll
  for (int i = 0; i < 12; ++i) xv[i] = h[b * 12 + i];
#pragma unroll
  for (int i = 0; i < 12; ++i) xv[12 + i] = p[b * 12 + i];
  float h1[28];
  const float* w1 = W1 + t * 28 * 24;
#pragma unroll 1
  for (int i = 0; i < 28; ++i) {
    float s = b1[t * 28 + i];
#pragma unroll
    for (int j = 0; j < 24; ++j) s = fmaf(w1[i * 24 + j], xv[j], s);
    h1[i] = fmaxf(s, 0.f);
  }
  float h2[14];
  const float* w2 = W2 + t * 14 * 28;
#pragma unroll 1
  for (int i = 0; i < 14; ++i) {
    float s = b2[t * 14 + i];
#pragma unroll
    for (int j = 0; j < 28; ++j) s = fmaf(w2[i * 28 + j], h1[j], s);
    h2[i] = fmaxf(s, 0.f);
  }
  const float* w3 = W3 + t * 5 * 14;
#pragma unroll
  for (int i = 0; i < 5; ++i) {
    float s = b3[t * 5 + i];
#pragma unroll
    for (int j = 0; j < 14; ++j) s = fmaf(w3[i * 14 + j], h2[j], s);
    out[b * 5 + i] = s;
  }
}

extern "C" void kernel_launch(void* const* d_in, const int* in_sizes, int n_in,
                              void* d_out, int out_size, void* d_ws, size_t ws_size,
                              hipStream_t stream) {
  const float* x_s  = (const float*)d_in[0];
  const float* x_p  = (const float*)d_in[1];
  const int*   tt   = (const int*)d_in[2];
  const int*   dom  = (const int*)d_in[3];
  const float* WinW = (const float*)d_in[4];
  const float* Winb = (const float*)d_in[5];
  const float* WhW  = (const float*)d_in[6];
  const float* Whb  = (const float*)d_in[7];
  const float* WfcW = (const float*)d_in[8];
  const float* Wfcb = (const float*)d_in[9];
  const float* PcW  = (const float*)d_in[10];
  const float* Pcb  = (const float*)d_in[11];
  const float* PlW  = (const float*)d_in[12];
  const float* Plb  = (const float*)d_in[13];
  const float* H1W  = (const float*)d_in[14];
  const float* H1b  = (const float*)d_in[15];
  const float* H2W  = (const float*)d_in[16];
  const float* H2b  = (const float*)d_in[17];
  const float* H3W  = (const float*)d_in[18];
  const float* H3b  = (const float*)d_in[19];
  float* out = (float*)d_out;

  char* ws = (char*)d_ws;
  __half* Bp   = (__half*)(ws + 0);        // 33,792 B
  float*  b48  = (float*)(ws + 33792);     // 192
  __half* B36  = (__half*)(ws + 33984);    // 6,144
  __half* B12  = (__half*)(ws + 40128);    // 2,048
  __half* Wpp  = (__half*)(ws + 42176);    // [12][12288] f16
  __half* Wshp = (__half*)(ws + 337088);   // [12][2304]  f16
  float*  hb   = (float*)(ws + 392384);    // [1024][12]
  float*  pb   = (float*)(ws + 441536);    // [1024][12]

  k_prepack_small<<<1, 256, 0, stream>>>(WhW, Whb, WinW, PcW, dom, Bp, b48, B36, B12);
  k_prepack_fcp<<<96, 256, 0, stream>>>(PlW, dom, WfcW, Wpp, Wshp);
  k_priv<<<1024, 256, 0, stream>>>(x_p, B12, Pcb, dom, Wpp, Plb, pb);
  k_tower<<<1024, 512, 154496, stream>>>(x_s, B36, Winb, Bp, b48, Wshp, Wfcb, hb);
  k_heads<<<4, 256, 0, stream>>>(hb, pb, tt, H1W, H1b, H2W, H2b, H3W, H3b, out);
}